// Round 11
// baseline (445.090 us; speedup 1.0000x reference)
//
#include <hip/hip_runtime.h>

#define N_USERS   100000
#define N_ITEMS   50000
#define N_NODES   150000
#define EMBED_DIM 64
#define COVER_DIM 512
#define N_EDGES   4000000
#define N_LAYERS  3

// partition geometry
#define FINE_ROWS 128                 // rows per fine bucket
#define NF        1184                // 37*32 fine buckets (covers 151552 rows)
#define NC        37                  // coarse buckets (4096 rows each)
#define TILE_E    4096                // edges per partition tile
#define NT_A      ((N_EDGES + TILE_E - 1) / TILE_E)   // 977
#define BSORT_CAP 4096                // mean bucket 3378, sd 58 -> 12 sigma

typedef __attribute__((ext_vector_type(4))) _Float16 half4;
typedef __attribute__((ext_vector_type(8))) _Float16 f16x8;
typedef __attribute__((ext_vector_type(2))) __fp16   pk16x2;  // cvt_pkrtz result type
typedef __attribute__((ext_vector_type(4))) float    f32x4;

// ---------------------------------------------------------------------------
// x16[0:N_USERS] = fp16(user_emb) ; acc = user_emb (fp32)
// ---------------------------------------------------------------------------
__global__ void build_user_x(const float* __restrict__ user_emb,
                             half4* __restrict__ x16,
                             float* __restrict__ acc) {
    int i = blockIdx.x * blockDim.x + threadIdx.x;
    const int n4 = N_USERS * EMBED_DIM / 4;
    if (i < n4) {
        float4 v = reinterpret_cast<const float4*>(user_emb)[i];
        half4 h;
        h.x = (_Float16)v.x; h.y = (_Float16)v.y;
        h.z = (_Float16)v.z; h.w = (_Float16)v.w;
        x16[i] = h;
        reinterpret_cast<float4*>(acc)[i] = v;
    }
}

// ---------------------------------------------------------------------------
// W [64][512] f32 -> Wh [64][512] fp16 (same layout). Trivial.
// ---------------------------------------------------------------------------
__global__ void conv_W(const float* __restrict__ W, half4* __restrict__ Wh) {
    int i = blockIdx.x * blockDim.x + threadIdx.x;     // float4 index
    const int n4 = EMBED_DIM * COVER_DIM / 4;          // 8192
    if (i < n4) {
        float4 v = reinterpret_cast<const float4*>(W)[i];
        half4 h;
        h.x = (_Float16)v.x; h.y = (_Float16)v.y;
        h.z = (_Float16)v.z; h.w = (_Float16)v.w;
        Wh[i] = h;
    }
}

// ---------------------------------------------------------------------------
// MFMA GEMM: proj = item_cover[50000x512] @ W^T[512x64]
// One wave per 16 items x 64 dims; 4 MFMA 16x16x32 per K-step, 16 K-steps.
// ---------------------------------------------------------------------------
__global__ __launch_bounds__(256) void build_item_x_mfma(
        const float* __restrict__ item_emb,
        const _Float16* __restrict__ Wh,
        const float* __restrict__ item_cover,
        const float* __restrict__ has_cover,
        half4* __restrict__ x16_items,
        float* __restrict__ acc_items) {
    const int tid  = threadIdx.x;
    const int lane = tid & 63;
    const int wid  = tid >> 6;
    const int mw   = blockIdx.x * 64 + wid * 16;   // wave's first item row
    const int cl   = lane & 15;
    const int kh   = lane >> 4;                    // 0..3 K-subblock

    int arow = mw + cl;
    if (arow >= N_ITEMS) arow = N_ITEMS - 1;       // clamp (dup read, safe)
    const float* ap = item_cover + (size_t)arow * COVER_DIM + kh * 8;
    const f16x8* bp = reinterpret_cast<const f16x8*>(Wh)
                      + (size_t)cl * (COVER_DIM / 8) + kh;

    f32x4 acc0 = {0.f, 0.f, 0.f, 0.f};
    f32x4 acc1 = {0.f, 0.f, 0.f, 0.f};
    f32x4 acc2 = {0.f, 0.f, 0.f, 0.f};
    f32x4 acc3 = {0.f, 0.f, 0.f, 0.f};

#pragma unroll 4
    for (int k0 = 0; k0 < COVER_DIM; k0 += 32) {
        float4 a0 = *reinterpret_cast<const float4*>(ap + k0);
        float4 a1 = *reinterpret_cast<const float4*>(ap + k0 + 4);
        pk16x2 p0 = __builtin_amdgcn_cvt_pkrtz(a0.x, a0.y);
        pk16x2 p1 = __builtin_amdgcn_cvt_pkrtz(a0.z, a0.w);
        pk16x2 p2 = __builtin_amdgcn_cvt_pkrtz(a1.x, a1.y);
        pk16x2 p3 = __builtin_amdgcn_cvt_pkrtz(a1.z, a1.w);
        f16x8 af;
        af[0] = (_Float16)p0[0]; af[1] = (_Float16)p0[1];
        af[2] = (_Float16)p1[0]; af[3] = (_Float16)p1[1];
        af[4] = (_Float16)p2[0]; af[5] = (_Float16)p2[1];
        af[6] = (_Float16)p3[0]; af[7] = (_Float16)p3[1];

        int kq = k0 >> 3;                          // k0/8 in f16x8 units
        f16x8 b0 = bp[kq];                         // dims  0..15
        f16x8 b1 = bp[1024 + kq];                  // dims 16..31 (16 rows * 64)
        f16x8 b2 = bp[2048 + kq];                  // dims 32..47
        f16x8 b3 = bp[3072 + kq];                  // dims 48..63

        acc0 = __builtin_amdgcn_mfma_f32_16x16x32_f16(af, b0, acc0, 0, 0, 0);
        acc1 = __builtin_amdgcn_mfma_f32_16x16x32_f16(af, b1, acc1, 0, 0, 0);
        acc2 = __builtin_amdgcn_mfma_f32_16x16x32_f16(af, b2, acc2, 0, 0, 0);
        acc3 = __builtin_amdgcn_mfma_f32_16x16x32_f16(af, b3, acc3, 0, 0, 0);
    }

#pragma unroll
    for (int j = 0; j < 4; ++j) {
        int item = mw + kh * 4 + j;
        if (item < N_ITEMS) {
            float hc = has_cover[item];
            const float* ep = item_emb + (size_t)item * EMBED_DIM;
            float v0 = ep[ 0 + cl] + hc * acc0[j];
            float v1 = ep[16 + cl] + hc * acc1[j];
            float v2 = ep[32 + cl] + hc * acc2[j];
            float v3 = ep[48 + cl] + hc * acc3[j];
            _Float16* xp = reinterpret_cast<_Float16*>(x16_items)
                           + (size_t)item * EMBED_DIM;
            float* cp = acc_items + (size_t)item * EMBED_DIM;
            xp[ 0 + cl] = (_Float16)v0;  cp[ 0 + cl] = v0;
            xp[16 + cl] = (_Float16)v1;  cp[16 + cl] = v1;
            xp[32 + cl] = (_Float16)v2;  cp[32 + cl] = v2;
            xp[48 + cl] = (_Float16)v3;  cp[48 + cl] = v3;
        }
    }
}

// ---------------------------------------------------------------------------
// K1: fine-bucket histogram (bucket = row >> 7), LDS-staged.
// ---------------------------------------------------------------------------
__global__ __launch_bounds__(256) void fine_hist(const int* __restrict__ rows,
                                                 int* __restrict__ hist) {
    __shared__ int h[NF];
    int tid = threadIdx.x;
    for (int i = tid; i < NF; i += 256) h[i] = 0;
    __syncthreads();
    const int n4 = N_EDGES / 4;
    int stride = gridDim.x * 256;
    for (int i = blockIdx.x * 256 + tid; i < n4; i += stride) {
        int4 r = reinterpret_cast<const int4*>(rows)[i];
        atomicAdd(&h[r.x >> 7], 1);
        atomicAdd(&h[r.y >> 7], 1);
        atomicAdd(&h[r.z >> 7], 1);
        atomicAdd(&h[r.w >> 7], 1);
    }
    __syncthreads();
    for (int i = tid; i < NF; i += 256)
        if (h[i]) atomicAdd(&hist[i], h[i]);
}

// ---------------------------------------------------------------------------
// K2: scan 1184 fine counts -> fine_base[NF+1], fine_cursor, coarse_cursor.
// ---------------------------------------------------------------------------
__global__ __launch_bounds__(256) void scan_fine(const int* __restrict__ hist,
                                                 int* __restrict__ fine_base,
                                                 int* __restrict__ fine_cursor,
                                                 int* __restrict__ coarse_cursor) {
    __shared__ int s[256];
    int tid = threadIdx.x;
    const int CH = 5;
    int lo = tid * CH;
    int loc[CH];
    int sum = 0;
#pragma unroll
    for (int i = 0; i < CH; ++i) {
        int idx = lo + i;
        int v = (idx < NF) ? hist[idx] : 0;
        loc[i] = sum;
        sum += v;
    }
    s[tid] = sum;
    __syncthreads();
    for (int off = 1; off < 256; off <<= 1) {
        int t = (tid >= off) ? s[tid - off] : 0;
        __syncthreads();
        s[tid] += t;
        __syncthreads();
    }
    int base = (tid == 0) ? 0 : s[tid - 1];
#pragma unroll
    for (int i = 0; i < CH; ++i) {
        int idx = lo + i;
        if (idx < NF) {
            int b = base + loc[i];
            fine_base[idx]   = b;
            fine_cursor[idx] = b;
        }
    }
    if (tid == 255) fine_base[NF] = s[255];
    __syncthreads();
    if (tid < NC) coarse_cursor[tid] = fine_base[tid * 32];
}

// ---------------------------------------------------------------------------
// K3: pass A — partition edges into 37 coarse buckets (4096 rows each).
// ---------------------------------------------------------------------------
__global__ __launch_bounds__(256) void part_coarse(
        const int* __restrict__ rows,
        const int* __restrict__ cols,
        const float* __restrict__ vals,
        int* __restrict__ coarse_cursor,
        uint2* __restrict__ out) {
    __shared__ unsigned s_lo[TILE_E];
    __shared__ unsigned s_hi[TILE_E];
    __shared__ unsigned char s_bin[TILE_E];
    __shared__ int s_hist[NC];
    __shared__ int s_base[NC];
    __shared__ int s_cur[NC];
    __shared__ int s_gbase[NC];

    const int tid  = threadIdx.x;
    const long long tbeg = (long long)blockIdx.x * TILE_E;
    const int cnt  = (int)((N_EDGES - tbeg) < TILE_E ? (N_EDGES - tbeg) : TILE_E);

    for (int i = tid; i < NC; i += 256) s_hist[i] = 0;
    __syncthreads();

    int r[16];
#pragma unroll
    for (int q = 0; q < 4; ++q) {
        int o = q * 1024 + tid * 4;
        if (o < cnt) {
            int4 rr = *reinterpret_cast<const int4*>(rows + tbeg + o);
            r[q*4+0] = rr.x; r[q*4+1] = rr.y; r[q*4+2] = rr.z; r[q*4+3] = rr.w;
            atomicAdd(&s_hist[rr.x >> 12], 1);
            atomicAdd(&s_hist[rr.y >> 12], 1);
            atomicAdd(&s_hist[rr.z >> 12], 1);
            atomicAdd(&s_hist[rr.w >> 12], 1);
        }
    }
    __syncthreads();

    if (tid == 0) {
        int run = 0;
        for (int b = 0; b < NC; ++b) {
            s_base[b] = run;
            s_cur[b]  = run;
            run += s_hist[b];
        }
    }
    __syncthreads();

#pragma unroll
    for (int q = 0; q < 4; ++q) {
        int o = q * 1024 + tid * 4;
        if (o < cnt) {
            int4   cc = *reinterpret_cast<const int4*>(cols + tbeg + o);
            float4 vv = *reinterpret_cast<const float4*>(vals + tbeg + o);
            int rr; int b; int pos;
            rr = r[q*4+0]; b = rr >> 12; pos = atomicAdd(&s_cur[b], 1);
            s_lo[pos] = __float_as_uint(vv.x);
            s_hi[pos] = ((unsigned)(rr & 4095) << 18) | (unsigned)cc.x;
            s_bin[pos] = (unsigned char)b;
            rr = r[q*4+1]; b = rr >> 12; pos = atomicAdd(&s_cur[b], 1);
            s_lo[pos] = __float_as_uint(vv.y);
            s_hi[pos] = ((unsigned)(rr & 4095) << 18) | (unsigned)cc.y;
            s_bin[pos] = (unsigned char)b;
            rr = r[q*4+2]; b = rr >> 12; pos = atomicAdd(&s_cur[b], 1);
            s_lo[pos] = __float_as_uint(vv.z);
            s_hi[pos] = ((unsigned)(rr & 4095) << 18) | (unsigned)cc.z;
            s_bin[pos] = (unsigned char)b;
            rr = r[q*4+3]; b = rr >> 12; pos = atomicAdd(&s_cur[b], 1);
            s_lo[pos] = __float_as_uint(vv.w);
            s_hi[pos] = ((unsigned)(rr & 4095) << 18) | (unsigned)cc.w;
            s_bin[pos] = (unsigned char)b;
        }
    }
    __syncthreads();

    if (tid < NC) {
        int c = s_hist[tid];
        s_gbase[tid] = c ? atomicAdd(&coarse_cursor[tid], c) : 0;
    }
    __syncthreads();

    for (int i = tid; i < cnt; i += 256) {
        int b = s_bin[i];
        int g = s_gbase[b] + (i - s_base[b]);
        out[g] = make_uint2(s_lo[i], s_hi[i]);
    }
}

// ---------------------------------------------------------------------------
// K4: pass B — partition each coarse region into 32 fine buckets (128 rows).
// ---------------------------------------------------------------------------
__global__ __launch_bounds__(256) void part_fine(
        const uint2* __restrict__ in,
        const int* __restrict__ fine_base,
        int* __restrict__ fine_cursor,
        uint2* __restrict__ out) {
    __shared__ unsigned s_lo[TILE_E];
    __shared__ unsigned s_hi[TILE_E];
    __shared__ unsigned char s_bin[TILE_E];
    __shared__ int s_hist[32];
    __shared__ int s_base[32];
    __shared__ int s_cur[32];
    __shared__ int s_gbase[32];

    const int tid = threadIdx.x;
    const int cb  = blockIdx.y;
    const int cbeg = fine_base[cb * 32];
    const int cend = fine_base[(cb + 1) * 32];
    const int tbeg = cbeg + blockIdx.x * TILE_E;
    if (tbeg >= cend) return;
    const int cnt = (cend - tbeg) < TILE_E ? (cend - tbeg) : TILE_E;

    if (tid < 32) s_hist[tid] = 0;
    __syncthreads();

    unsigned elo[16], ehi[16];
#pragma unroll
    for (int j = 0; j < 16; ++j) {
        int o = tid + j * 256;
        if (o < cnt) {
            uint2 e = in[tbeg + o];
            elo[j] = e.x; ehi[j] = e.y;
            atomicAdd(&s_hist[ehi[j] >> 25], 1);
        }
    }
    __syncthreads();

    if (tid == 0) {
        int run = 0;
        for (int b = 0; b < 32; ++b) {
            s_base[b] = run;
            s_cur[b]  = run;
            run += s_hist[b];
        }
    }
    __syncthreads();

#pragma unroll
    for (int j = 0; j < 16; ++j) {
        int o = tid + j * 256;
        if (o < cnt) {
            int b = ehi[j] >> 25;
            int pos = atomicAdd(&s_cur[b], 1);
            s_lo[pos]  = elo[j];
            s_hi[pos]  = ehi[j] & 0x1FFFFFFu;
            s_bin[pos] = (unsigned char)b;
        }
    }
    __syncthreads();

    if (tid < 32) {
        int c = s_hist[tid];
        s_gbase[tid] = c ? atomicAdd(&fine_cursor[cb * 32 + tid], c) : 0;
    }
    __syncthreads();

    for (int i = tid; i < cnt; i += 256) {
        int b = s_bin[i];
        int g = s_gbase[b] + (i - s_base[b]);
        out[g] = make_uint2(s_lo[i], s_hi[i]);
    }
}

// ---------------------------------------------------------------------------
// K5: per-bucket exact-row counting sort (LDS) -> CSR order + row_ptr.
// ---------------------------------------------------------------------------
__global__ __launch_bounds__(256) void bucket_sort(
        const uint2* __restrict__ in,
        const int* __restrict__ fine_base,
        uint2* __restrict__ out,
        int* __restrict__ row_ptr) {
    __shared__ unsigned s_lo[BSORT_CAP];
    __shared__ unsigned s_hi[BSORT_CAP];
    __shared__ int s_hist[FINE_ROWS];
    __shared__ int s_scan[FINE_ROWS];
    __shared__ int s_cur[FINE_ROWS];

    const int f   = blockIdx.x;
    const int tid = threadIdx.x;
    const int beg = fine_base[f];
    const int end = fine_base[f + 1];
    const int cnt = end - beg;

    if (tid < FINE_ROWS) s_hist[tid] = 0;
    __syncthreads();

    unsigned elo[16], ehi[16];
#pragma unroll
    for (int j = 0; j < 16; ++j) {
        int o = tid + j * 256;
        if (o < cnt) {
            uint2 e = in[beg + o];
            elo[j] = e.x; ehi[j] = e.y;
            atomicAdd(&s_hist[ehi[j] >> 18], 1);
        }
    }
    __syncthreads();

    if (tid < FINE_ROWS) s_scan[tid] = s_hist[tid];
    __syncthreads();
    for (int off = 1; off < FINE_ROWS; off <<= 1) {
        int v = 0;
        if (tid < FINE_ROWS && tid >= off) v = s_scan[tid - off];
        __syncthreads();
        if (tid < FINE_ROWS) s_scan[tid] += v;
        __syncthreads();
    }
    if (tid < FINE_ROWS) {
        int excl = s_scan[tid] - s_hist[tid];
        s_cur[tid] = excl;
        int grow = f * FINE_ROWS + tid;
        if (grow <= N_NODES) row_ptr[grow] = beg + excl;
    }
    __syncthreads();

#pragma unroll
    for (int j = 0; j < 16; ++j) {
        int o = tid + j * 256;
        if (o < cnt) {
            int r = (int)(ehi[j] >> 18);
            int pos = atomicAdd(&s_cur[r], 1);
            s_lo[pos] = elo[j];
            s_hi[pos] = ehi[j];
        }
    }
    __syncthreads();

    for (int i = tid; i < cnt; i += 256)
        out[beg + i] = make_uint2(s_lo[i], s_hi[i]);
}

// ---------------------------------------------------------------------------
// K6: CSR SpMM, one wave per row; quarter-wave handles 4 adjacent edges
// per iteration (stride 16) -> 16 independent x-gathers in flight per wave.
// fp16 gathers, fp32 accumulate. Fused acc update.
// ---------------------------------------------------------------------------
__global__ __launch_bounds__(256) void spmm_csr(const int* __restrict__ row_ptr,
                                                const uint2* __restrict__ ecv,
                                                const half4* __restrict__ x16,
                                                half4* __restrict__ y16,
                                                float* __restrict__ acc,
                                                float scale, int write_y) {
    int wave = (int)((blockIdx.x * blockDim.x + threadIdx.x) >> 6);
    int lane = threadIdx.x & 63;
    if (wave >= N_NODES) return;
    int row  = wave;
    int beg  = row_ptr[row];
    int end  = row_ptr[row + 1];
    int esub = lane >> 4;
    int p    = lane & 15;

    float4 a = make_float4(0.f, 0.f, 0.f, 0.f);
    int j = beg + esub * 4;
    // quad iterations: edges j..j+3, stride 16 (4 groups x 4)
    for (; j + 4 <= end; j += 16) {
        uint2 cv0 = ecv[j];
        uint2 cv1 = ecv[j + 1];
        uint2 cv2 = ecv[j + 2];
        uint2 cv3 = ecv[j + 3];
        int c0 = (int)(cv0.y & 0x3FFFFu);
        int c1 = (int)(cv1.y & 0x3FFFFu);
        int c2 = (int)(cv2.y & 0x3FFFFu);
        int c3 = (int)(cv3.y & 0x3FFFFu);
        half4 xv0 = x16[(size_t)c0 * 16 + p];
        half4 xv1 = x16[(size_t)c1 * 16 + p];
        half4 xv2 = x16[(size_t)c2 * 16 + p];
        half4 xv3 = x16[(size_t)c3 * 16 + p];
        float v0 = __uint_as_float(cv0.x);
        float v1 = __uint_as_float(cv1.x);
        float v2 = __uint_as_float(cv2.x);
        float v3 = __uint_as_float(cv3.x);
        a.x += v0 * (float)xv0.x + v1 * (float)xv1.x;
        a.y += v0 * (float)xv0.y + v1 * (float)xv1.y;
        a.z += v0 * (float)xv0.z + v1 * (float)xv1.z;
        a.w += v0 * (float)xv0.w + v1 * (float)xv1.w;
        a.x += v2 * (float)xv2.x + v3 * (float)xv3.x;
        a.y += v2 * (float)xv2.y + v3 * (float)xv3.y;
        a.z += v2 * (float)xv2.z + v3 * (float)xv3.z;
        a.w += v2 * (float)xv2.w + v3 * (float)xv3.w;
    }
    // leftover (<4) edges for this group
    int jend = j + 4 < end ? j + 4 : end;
    for (; j < jend; ++j) {
        uint2 cv = ecv[j];
        int c = (int)(cv.y & 0x3FFFFu);
        half4 xv = x16[(size_t)c * 16 + p];
        float v = __uint_as_float(cv.x);
        a.x += v * (float)xv.x;
        a.y += v * (float)xv.y;
        a.z += v * (float)xv.z;
        a.w += v * (float)xv.w;
    }
#pragma unroll
    for (int m = 16; m <= 32; m <<= 1) {
        a.x += __shfl_xor(a.x, m, 64);
        a.y += __shfl_xor(a.y, m, 64);
        a.z += __shfl_xor(a.z, m, 64);
        a.w += __shfl_xor(a.w, m, 64);
    }
    if (esub == 0) {
        size_t idx = (size_t)row * 16 + p;
        if (write_y) {
            half4 h;
            h.x = (_Float16)a.x; h.y = (_Float16)a.y;
            h.z = (_Float16)a.z; h.w = (_Float16)a.w;
            y16[idx] = h;
        }
        float4 av = reinterpret_cast<float4*>(acc)[idx];
        av.x = (av.x + a.x) * scale;
        av.y = (av.y + a.y) * scale;
        av.z = (av.z + a.z) * scale;
        av.w = (av.w + a.w) * scale;
        reinterpret_cast<float4*>(acc)[idx] = av;
    }
}

extern "C" void kernel_launch(void* const* d_in, const int* in_sizes, int n_in,
                              void* d_out, int out_size, void* d_ws, size_t ws_size,
                              hipStream_t stream) {
    const float* user_emb   = (const float*)d_in[0];
    const float* item_emb   = (const float*)d_in[1];
    const float* cover_W    = (const float*)d_in[2];
    const float* item_cover = (const float*)d_in[3];
    const float* has_cover  = (const float*)d_in[4];
    const float* adj_vals   = (const float*)d_in[5];
    const int*   adj_rows   = (const int*)d_in[6];
    const int*   adj_cols   = (const int*)d_in[7];

    float* acc = (float*)d_out;  // [N_NODES][64] fp32

    const size_t feat16_bytes = (size_t)N_NODES * EMBED_DIM * 2;  // 19.2 MB

    char* base = (char*)d_ws;
    size_t off = 0;
    auto take = [&](size_t bytes) {
        char* p = base + off;
        off += (bytes + 255) & ~(size_t)255;
        return p;
    };
    half4* x16           = (half4*)take(feat16_bytes);
    half4* y16           = (half4*)take(feat16_bytes);
    uint2* ecv_a         = (uint2*)take((size_t)N_EDGES * sizeof(uint2));  // 32 MB
    uint2* ecv_b         = (uint2*)take((size_t)N_EDGES * sizeof(uint2));  // 32 MB
    int*   hist          = (int*)take((size_t)NF * sizeof(int));
    int*   fine_base     = (int*)take((size_t)(NF + 1) * sizeof(int));
    int*   fine_cursor   = (int*)take((size_t)NF * sizeof(int));
    int*   coarse_cursor = (int*)take((size_t)NC * sizeof(int));
    int*   row_ptr       = (int*)take((size_t)(N_NODES + 1) * sizeof(int));
    _Float16* Wh         = (_Float16*)take((size_t)EMBED_DIM * COVER_DIM * 2);
    (void)ws_size;  // ~104 MB needed; proven available (R6-R10 ran ~104 MB)

    // ---- x0 = concat(user_emb, item_emb + cover_proj); acc = x0 ----
    {
        int n4 = N_USERS * EMBED_DIM / 4;
        build_user_x<<<(n4 + 255) / 256, 256, 0, stream>>>(user_emb, x16, acc);
    }
    conv_W<<<(EMBED_DIM * COVER_DIM / 4 + 255) / 256, 256, 0, stream>>>(
        cover_W, (half4*)Wh);
    {
        int grid = (N_ITEMS + 63) / 64;   // 782 blocks, 4 waves x 16 items
        build_item_x_mfma<<<grid, 256, 0, stream>>>(
            item_emb, Wh, item_cover, has_cover,
            x16 + (size_t)N_USERS * 16,
            acc + (size_t)N_USERS * EMBED_DIM);
    }

    // ---- CSR build: hist -> scan -> coarse -> fine -> exact-row sort ----
    (void)hipMemsetAsync(hist, 0, (size_t)NF * sizeof(int), stream);
    fine_hist<<<256, 256, 0, stream>>>(adj_rows, hist);
    scan_fine<<<1, 256, 0, stream>>>(hist, fine_base, fine_cursor, coarse_cursor);
    part_coarse<<<NT_A, 256, 0, stream>>>(adj_rows, adj_cols, adj_vals,
                                          coarse_cursor, ecv_a);
    part_fine<<<dim3(32, NC), 256, 0, stream>>>(ecv_a, fine_base,
                                                fine_cursor, ecv_b);
    bucket_sort<<<NF, 256, 0, stream>>>(ecv_b, fine_base, ecv_a, row_ptr);

    // ---- 3 propagation layers, acc update fused ----
    half4* x = x16;
    half4* y = y16;
    for (int l = 0; l < N_LAYERS; ++l) {
        bool last = (l == N_LAYERS - 1);
        int grid = (N_NODES + 3) / 4;   // 4 waves (rows) per 256-thread block
        spmm_csr<<<grid, 256, 0, stream>>>(
            row_ptr, ecv_a, x, y, acc,
            last ? 0.25f : 1.0f, last ? 0 : 1);
        half4* tmp = x; x = y; y = tmp;
    }
}

// Round 12
// 436.520 us; speedup vs baseline: 1.0196x; 1.0196x over previous
//
#include <hip/hip_runtime.h>

#define N_USERS   100000
#define N_ITEMS   50000
#define N_NODES   150000
#define EMBED_DIM 64
#define COVER_DIM 512
#define N_EDGES   4000000
#define N_LAYERS  3

// partition geometry
#define FINE_ROWS 128                 // rows per fine bucket
#define NF        1184                // 37*32 fine buckets (covers 151552 rows)
#define NC        37                  // coarse buckets (4096 rows each)
#define TILE_E    4096                // edges per partition tile
#define NT_A      ((N_EDGES + TILE_E - 1) / TILE_E)   // 977
#define BSORT_CAP 4096                // mean bucket 3378, sd 58 -> 12 sigma

typedef __attribute__((ext_vector_type(4))) _Float16 half4;
typedef __attribute__((ext_vector_type(8))) _Float16 f16x8;
typedef __attribute__((ext_vector_type(2))) __fp16   pk16x2;  // cvt_pkrtz result type
typedef __attribute__((ext_vector_type(4))) float    f32x4;

// ---------------------------------------------------------------------------
// x16[0:N_USERS] = fp16(user_emb) ; acc = user_emb (fp32).
// Also converts W -> Wh fp16 (first 8192 float4s of the grid).
// ---------------------------------------------------------------------------
__global__ void build_user_x(const float* __restrict__ user_emb,
                             half4* __restrict__ x16,
                             float* __restrict__ acc,
                             const float* __restrict__ W,
                             half4* __restrict__ Wh) {
    int i = blockIdx.x * blockDim.x + threadIdx.x;
    const int n4 = N_USERS * EMBED_DIM / 4;
    if (i < n4) {
        float4 v = reinterpret_cast<const float4*>(user_emb)[i];
        half4 h;
        h.x = (_Float16)v.x; h.y = (_Float16)v.y;
        h.z = (_Float16)v.z; h.w = (_Float16)v.w;
        x16[i] = h;
        reinterpret_cast<float4*>(acc)[i] = v;
    }
    if (i < EMBED_DIM * COVER_DIM / 4) {
        float4 v = reinterpret_cast<const float4*>(W)[i];
        half4 h;
        h.x = (_Float16)v.x; h.y = (_Float16)v.y;
        h.z = (_Float16)v.z; h.w = (_Float16)v.w;
        Wh[i] = h;
    }
}

// ---------------------------------------------------------------------------
// MFMA GEMM: proj = item_cover[50000x512] @ W^T[512x64]
// Block = 4 waves = 64 items. A staged through LDS in 64x64 f32 chunks
// (coalesced float4 global loads; pad 68 -> 2-way LDS aliasing = free).
// Per K-chunk: 2 K-steps x 4 MFMA 16x16x32.
// Epilogue: o = item_emb + has_cover*proj -> x16 (fp16), acc (fp32).
// ---------------------------------------------------------------------------
__global__ __launch_bounds__(256) void build_item_x_mfma(
        const float* __restrict__ item_emb,
        const _Float16* __restrict__ Wh,
        const float* __restrict__ item_cover,
        const float* __restrict__ has_cover,
        half4* __restrict__ x16_items,
        float* __restrict__ acc_items) {
    __shared__ float As[64][68];                   // 17.4 KB

    const int tid  = threadIdx.x;
    const int lane = tid & 63;
    const int wid  = tid >> 6;
    const int m0   = blockIdx.x * 64;              // block's first item row
    const int mw   = m0 + wid * 16;                // wave's first item row
    const int cl   = lane & 15;
    const int kh   = lane >> 4;                    // 0..3 K-subblock

    const f16x8* bp = reinterpret_cast<const f16x8*>(Wh)
                      + (size_t)cl * (COVER_DIM / 8) + kh;

    f32x4 acc0 = {0.f, 0.f, 0.f, 0.f};
    f32x4 acc1 = {0.f, 0.f, 0.f, 0.f};
    f32x4 acc2 = {0.f, 0.f, 0.f, 0.f};
    f32x4 acc3 = {0.f, 0.f, 0.f, 0.f};

    for (int ch = 0; ch < COVER_DIM / 64; ++ch) {  // 8 chunks of K=64
        // ---- stage A chunk: 64 rows x 64 cols f32, coalesced ----
#pragma unroll
        for (int it = 0; it < 4; ++it) {
            int q   = tid + it * 256;              // 0..1023
            int r   = q >> 4;                      // 0..63
            int c4  = q & 15;
            int row = m0 + r;
            if (row >= N_ITEMS) row = N_ITEMS - 1;
            float4 v = *reinterpret_cast<const float4*>(
                item_cover + (size_t)row * COVER_DIM + ch * 64 + c4 * 4);
            *reinterpret_cast<float4*>(&As[r][c4 * 4]) = v;
        }
        __syncthreads();

        // ---- 2 K-steps of 32 ----
#pragma unroll
        for (int ks = 0; ks < 2; ++ks) {
            const float* ar = &As[wid * 16 + cl][ks * 32 + kh * 8];
            pk16x2 p0 = __builtin_amdgcn_cvt_pkrtz(ar[0], ar[1]);
            pk16x2 p1 = __builtin_amdgcn_cvt_pkrtz(ar[2], ar[3]);
            pk16x2 p2 = __builtin_amdgcn_cvt_pkrtz(ar[4], ar[5]);
            pk16x2 p3 = __builtin_amdgcn_cvt_pkrtz(ar[6], ar[7]);
            f16x8 af;
            af[0] = (_Float16)p0[0]; af[1] = (_Float16)p0[1];
            af[2] = (_Float16)p1[0]; af[3] = (_Float16)p1[1];
            af[4] = (_Float16)p2[0]; af[5] = (_Float16)p2[1];
            af[6] = (_Float16)p3[0]; af[7] = (_Float16)p3[1];

            int kq = (ch * 64 + ks * 32) >> 3;     // in f16x8 units
            f16x8 b0 = bp[kq];
            f16x8 b1 = bp[1024 + kq];
            f16x8 b2 = bp[2048 + kq];
            f16x8 b3 = bp[3072 + kq];

            acc0 = __builtin_amdgcn_mfma_f32_16x16x32_f16(af, b0, acc0, 0, 0, 0);
            acc1 = __builtin_amdgcn_mfma_f32_16x16x32_f16(af, b1, acc1, 0, 0, 0);
            acc2 = __builtin_amdgcn_mfma_f32_16x16x32_f16(af, b2, acc2, 0, 0, 0);
            acc3 = __builtin_amdgcn_mfma_f32_16x16x32_f16(af, b3, acc3, 0, 0, 0);
        }
        __syncthreads();
    }

#pragma unroll
    for (int j = 0; j < 4; ++j) {
        int item = mw + kh * 4 + j;
        if (item < N_ITEMS) {
            float hc = has_cover[item];
            const float* ep = item_emb + (size_t)item * EMBED_DIM;
            float v0 = ep[ 0 + cl] + hc * acc0[j];
            float v1 = ep[16 + cl] + hc * acc1[j];
            float v2 = ep[32 + cl] + hc * acc2[j];
            float v3 = ep[48 + cl] + hc * acc3[j];
            _Float16* xp = reinterpret_cast<_Float16*>(x16_items)
                           + (size_t)item * EMBED_DIM;
            float* cp = acc_items + (size_t)item * EMBED_DIM;
            xp[ 0 + cl] = (_Float16)v0;  cp[ 0 + cl] = v0;
            xp[16 + cl] = (_Float16)v1;  cp[16 + cl] = v1;
            xp[32 + cl] = (_Float16)v2;  cp[32 + cl] = v2;
            xp[48 + cl] = (_Float16)v3;  cp[48 + cl] = v3;
        }
    }
}

// ---------------------------------------------------------------------------
// K1: fine-bucket histogram (bucket = row >> 7), LDS-staged.
// ---------------------------------------------------------------------------
__global__ __launch_bounds__(256) void fine_hist(const int* __restrict__ rows,
                                                 int* __restrict__ hist) {
    __shared__ int h[NF];
    int tid = threadIdx.x;
    for (int i = tid; i < NF; i += 256) h[i] = 0;
    __syncthreads();
    const int n4 = N_EDGES / 4;
    int stride = gridDim.x * 256;
    for (int i = blockIdx.x * 256 + tid; i < n4; i += stride) {
        int4 r = reinterpret_cast<const int4*>(rows)[i];
        atomicAdd(&h[r.x >> 7], 1);
        atomicAdd(&h[r.y >> 7], 1);
        atomicAdd(&h[r.z >> 7], 1);
        atomicAdd(&h[r.w >> 7], 1);
    }
    __syncthreads();
    for (int i = tid; i < NF; i += 256)
        if (h[i]) atomicAdd(&hist[i], h[i]);
}

// ---------------------------------------------------------------------------
// K2: scan 1184 fine counts -> fine_base[NF+1], fine_cursor, coarse_cursor.
// ---------------------------------------------------------------------------
__global__ __launch_bounds__(256) void scan_fine(const int* __restrict__ hist,
                                                 int* __restrict__ fine_base,
                                                 int* __restrict__ fine_cursor,
                                                 int* __restrict__ coarse_cursor) {
    __shared__ int s[256];
    int tid = threadIdx.x;
    const int CH = 5;
    int lo = tid * CH;
    int loc[CH];
    int sum = 0;
#pragma unroll
    for (int i = 0; i < CH; ++i) {
        int idx = lo + i;
        int v = (idx < NF) ? hist[idx] : 0;
        loc[i] = sum;
        sum += v;
    }
    s[tid] = sum;
    __syncthreads();
    for (int off = 1; off < 256; off <<= 1) {
        int t = (tid >= off) ? s[tid - off] : 0;
        __syncthreads();
        s[tid] += t;
        __syncthreads();
    }
    int base = (tid == 0) ? 0 : s[tid - 1];
#pragma unroll
    for (int i = 0; i < CH; ++i) {
        int idx = lo + i;
        if (idx < NF) {
            int b = base + loc[i];
            fine_base[idx]   = b;
            fine_cursor[idx] = b;
        }
    }
    if (tid == 255) fine_base[NF] = s[255];
    __syncthreads();
    if (tid < NC) coarse_cursor[tid] = fine_base[tid * 32];
}

// ---------------------------------------------------------------------------
// K3: pass A — partition edges into 37 coarse buckets (4096 rows each).
// ---------------------------------------------------------------------------
__global__ __launch_bounds__(256) void part_coarse(
        const int* __restrict__ rows,
        const int* __restrict__ cols,
        const float* __restrict__ vals,
        int* __restrict__ coarse_cursor,
        uint2* __restrict__ out) {
    __shared__ unsigned s_lo[TILE_E];
    __shared__ unsigned s_hi[TILE_E];
    __shared__ unsigned char s_bin[TILE_E];
    __shared__ int s_hist[NC];
    __shared__ int s_base[NC];
    __shared__ int s_cur[NC];
    __shared__ int s_gbase[NC];

    const int tid  = threadIdx.x;
    const long long tbeg = (long long)blockIdx.x * TILE_E;
    const int cnt  = (int)((N_EDGES - tbeg) < TILE_E ? (N_EDGES - tbeg) : TILE_E);

    for (int i = tid; i < NC; i += 256) s_hist[i] = 0;
    __syncthreads();

    int r[16];
#pragma unroll
    for (int q = 0; q < 4; ++q) {
        int o = q * 1024 + tid * 4;
        if (o < cnt) {
            int4 rr = *reinterpret_cast<const int4*>(rows + tbeg + o);
            r[q*4+0] = rr.x; r[q*4+1] = rr.y; r[q*4+2] = rr.z; r[q*4+3] = rr.w;
            atomicAdd(&s_hist[rr.x >> 12], 1);
            atomicAdd(&s_hist[rr.y >> 12], 1);
            atomicAdd(&s_hist[rr.z >> 12], 1);
            atomicAdd(&s_hist[rr.w >> 12], 1);
        }
    }
    __syncthreads();

    if (tid == 0) {
        int run = 0;
        for (int b = 0; b < NC; ++b) {
            s_base[b] = run;
            s_cur[b]  = run;
            run += s_hist[b];
        }
    }
    __syncthreads();

#pragma unroll
    for (int q = 0; q < 4; ++q) {
        int o = q * 1024 + tid * 4;
        if (o < cnt) {
            int4   cc = *reinterpret_cast<const int4*>(cols + tbeg + o);
            float4 vv = *reinterpret_cast<const float4*>(vals + tbeg + o);
            int rr; int b; int pos;
            rr = r[q*4+0]; b = rr >> 12; pos = atomicAdd(&s_cur[b], 1);
            s_lo[pos] = __float_as_uint(vv.x);
            s_hi[pos] = ((unsigned)(rr & 4095) << 18) | (unsigned)cc.x;
            s_bin[pos] = (unsigned char)b;
            rr = r[q*4+1]; b = rr >> 12; pos = atomicAdd(&s_cur[b], 1);
            s_lo[pos] = __float_as_uint(vv.y);
            s_hi[pos] = ((unsigned)(rr & 4095) << 18) | (unsigned)cc.y;
            s_bin[pos] = (unsigned char)b;
            rr = r[q*4+2]; b = rr >> 12; pos = atomicAdd(&s_cur[b], 1);
            s_lo[pos] = __float_as_uint(vv.z);
            s_hi[pos] = ((unsigned)(rr & 4095) << 18) | (unsigned)cc.z;
            s_bin[pos] = (unsigned char)b;
            rr = r[q*4+3]; b = rr >> 12; pos = atomicAdd(&s_cur[b], 1);
            s_lo[pos] = __float_as_uint(vv.w);
            s_hi[pos] = ((unsigned)(rr & 4095) << 18) | (unsigned)cc.w;
            s_bin[pos] = (unsigned char)b;
        }
    }
    __syncthreads();

    if (tid < NC) {
        int c = s_hist[tid];
        s_gbase[tid] = c ? atomicAdd(&coarse_cursor[tid], c) : 0;
    }
    __syncthreads();

    for (int i = tid; i < cnt; i += 256) {
        int b = s_bin[i];
        int g = s_gbase[b] + (i - s_base[b]);
        out[g] = make_uint2(s_lo[i], s_hi[i]);
    }
}

// ---------------------------------------------------------------------------
// K4: pass B — partition each coarse region into 32 fine buckets (128 rows).
// ---------------------------------------------------------------------------
__global__ __launch_bounds__(256) void part_fine(
        const uint2* __restrict__ in,
        const int* __restrict__ fine_base,
        int* __restrict__ fine_cursor,
        uint2* __restrict__ out) {
    __shared__ unsigned s_lo[TILE_E];
    __shared__ unsigned s_hi[TILE_E];
    __shared__ unsigned char s_bin[TILE_E];
    __shared__ int s_hist[32];
    __shared__ int s_base[32];
    __shared__ int s_cur[32];
    __shared__ int s_gbase[32];

    const int tid = threadIdx.x;
    const int cb  = blockIdx.y;
    const int cbeg = fine_base[cb * 32];
    const int cend = fine_base[(cb + 1) * 32];
    const int tbeg = cbeg + blockIdx.x * TILE_E;
    if (tbeg >= cend) return;
    const int cnt = (cend - tbeg) < TILE_E ? (cend - tbeg) : TILE_E;

    if (tid < 32) s_hist[tid] = 0;
    __syncthreads();

    unsigned elo[16], ehi[16];
#pragma unroll
    for (int j = 0; j < 16; ++j) {
        int o = tid + j * 256;
        if (o < cnt) {
            uint2 e = in[tbeg + o];
            elo[j] = e.x; ehi[j] = e.y;
            atomicAdd(&s_hist[ehi[j] >> 25], 1);
        }
    }
    __syncthreads();

    if (tid == 0) {
        int run = 0;
        for (int b = 0; b < 32; ++b) {
            s_base[b] = run;
            s_cur[b]  = run;
            run += s_hist[b];
        }
    }
    __syncthreads();

#pragma unroll
    for (int j = 0; j < 16; ++j) {
        int o = tid + j * 256;
        if (o < cnt) {
            int b = ehi[j] >> 25;
            int pos = atomicAdd(&s_cur[b], 1);
            s_lo[pos]  = elo[j];
            s_hi[pos]  = ehi[j] & 0x1FFFFFFu;
            s_bin[pos] = (unsigned char)b;
        }
    }
    __syncthreads();

    if (tid < 32) {
        int c = s_hist[tid];
        s_gbase[tid] = c ? atomicAdd(&fine_cursor[cb * 32 + tid], c) : 0;
    }
    __syncthreads();

    for (int i = tid; i < cnt; i += 256) {
        int b = s_bin[i];
        int g = s_gbase[b] + (i - s_base[b]);
        out[g] = make_uint2(s_lo[i], s_hi[i]);
    }
}

// ---------------------------------------------------------------------------
// K5: per-bucket exact-row counting sort (LDS) -> CSR order + row_ptr.
// ---------------------------------------------------------------------------
__global__ __launch_bounds__(256) void bucket_sort(
        const uint2* __restrict__ in,
        const int* __restrict__ fine_base,
        uint2* __restrict__ out,
        int* __restrict__ row_ptr) {
    __shared__ unsigned s_lo[BSORT_CAP];
    __shared__ unsigned s_hi[BSORT_CAP];
    __shared__ int s_hist[FINE_ROWS];
    __shared__ int s_scan[FINE_ROWS];
    __shared__ int s_cur[FINE_ROWS];

    const int f   = blockIdx.x;
    const int tid = threadIdx.x;
    const int beg = fine_base[f];
    const int end = fine_base[f + 1];
    const int cnt = end - beg;

    if (tid < FINE_ROWS) s_hist[tid] = 0;
    __syncthreads();

    unsigned elo[16], ehi[16];
#pragma unroll
    for (int j = 0; j < 16; ++j) {
        int o = tid + j * 256;
        if (o < cnt) {
            uint2 e = in[beg + o];
            elo[j] = e.x; ehi[j] = e.y;
            atomicAdd(&s_hist[ehi[j] >> 18], 1);
        }
    }
    __syncthreads();

    if (tid < FINE_ROWS) s_scan[tid] = s_hist[tid];
    __syncthreads();
    for (int off = 1; off < FINE_ROWS; off <<= 1) {
        int v = 0;
        if (tid < FINE_ROWS && tid >= off) v = s_scan[tid - off];
        __syncthreads();
        if (tid < FINE_ROWS) s_scan[tid] += v;
        __syncthreads();
    }
    if (tid < FINE_ROWS) {
        int excl = s_scan[tid] - s_hist[tid];
        s_cur[tid] = excl;
        int grow = f * FINE_ROWS + tid;
        if (grow <= N_NODES) row_ptr[grow] = beg + excl;
    }
    __syncthreads();

#pragma unroll
    for (int j = 0; j < 16; ++j) {
        int o = tid + j * 256;
        if (o < cnt) {
            int r = (int)(ehi[j] >> 18);
            int pos = atomicAdd(&s_cur[r], 1);
            s_lo[pos] = elo[j];
            s_hi[pos] = ehi[j];
        }
    }
    __syncthreads();

    for (int i = tid; i < cnt; i += 256)
        out[beg + i] = make_uint2(s_lo[i], s_hi[i]);
}

// ---------------------------------------------------------------------------
// K6: CSR SpMM, one wave per row; quarter-wave handles 2 adjacent edges
// per iteration (stride 8) -> 8 independent x-gathers in flight per wave.
// (x4 unroll measured WORSE in R11 - MLP saturated at x2.)
// fp16 gathers, fp32 accumulate. Fused acc update.
// ---------------------------------------------------------------------------
__global__ __launch_bounds__(256) void spmm_csr(const int* __restrict__ row_ptr,
                                                const uint2* __restrict__ ecv,
                                                const half4* __restrict__ x16,
                                                half4* __restrict__ y16,
                                                float* __restrict__ acc,
                                                float scale, int write_y) {
    int wave = (int)((blockIdx.x * blockDim.x + threadIdx.x) >> 6);
    int lane = threadIdx.x & 63;
    if (wave >= N_NODES) return;
    int row  = wave;
    int beg  = row_ptr[row];
    int end  = row_ptr[row + 1];
    int esub = lane >> 4;
    int p    = lane & 15;

    float4 a = make_float4(0.f, 0.f, 0.f, 0.f);
    int j = beg + esub * 2;
    for (; j + 2 <= end; j += 8) {
        uint2 cv0 = ecv[j];
        uint2 cv1 = ecv[j + 1];
        int c0 = (int)(cv0.y & 0x3FFFFu);
        int c1 = (int)(cv1.y & 0x3FFFFu);
        half4 xv0 = x16[(size_t)c0 * 16 + p];
        half4 xv1 = x16[(size_t)c1 * 16 + p];
        float v0 = __uint_as_float(cv0.x);
        float v1 = __uint_as_float(cv1.x);
        a.x += v0 * (float)xv0.x;
        a.y += v0 * (float)xv0.y;
        a.z += v0 * (float)xv0.z;
        a.w += v0 * (float)xv0.w;
        a.x += v1 * (float)xv1.x;
        a.y += v1 * (float)xv1.y;
        a.z += v1 * (float)xv1.z;
        a.w += v1 * (float)xv1.w;
    }
    if (j < end) {
        uint2 cv = ecv[j];
        int c = (int)(cv.y & 0x3FFFFu);
        half4 xv = x16[(size_t)c * 16 + p];
        float v = __uint_as_float(cv.x);
        a.x += v * (float)xv.x;
        a.y += v * (float)xv.y;
        a.z += v * (float)xv.z;
        a.w += v * (float)xv.w;
    }
#pragma unroll
    for (int m = 16; m <= 32; m <<= 1) {
        a.x += __shfl_xor(a.x, m, 64);
        a.y += __shfl_xor(a.y, m, 64);
        a.z += __shfl_xor(a.z, m, 64);
        a.w += __shfl_xor(a.w, m, 64);
    }
    if (esub == 0) {
        size_t idx = (size_t)row * 16 + p;
        if (write_y) {
            half4 h;
            h.x = (_Float16)a.x; h.y = (_Float16)a.y;
            h.z = (_Float16)a.z; h.w = (_Float16)a.w;
            y16[idx] = h;
        }
        float4 av = reinterpret_cast<float4*>(acc)[idx];
        av.x = (av.x + a.x) * scale;
        av.y = (av.y + a.y) * scale;
        av.z = (av.z + a.z) * scale;
        av.w = (av.w + a.w) * scale;
        reinterpret_cast<float4*>(acc)[idx] = av;
    }
}

extern "C" void kernel_launch(void* const* d_in, const int* in_sizes, int n_in,
                              void* d_out, int out_size, void* d_ws, size_t ws_size,
                              hipStream_t stream) {
    const float* user_emb   = (const float*)d_in[0];
    const float* item_emb   = (const float*)d_in[1];
    const float* cover_W    = (const float*)d_in[2];
    const float* item_cover = (const float*)d_in[3];
    const float* has_cover  = (const float*)d_in[4];
    const float* adj_vals   = (const float*)d_in[5];
    const int*   adj_rows   = (const int*)d_in[6];
    const int*   adj_cols   = (const int*)d_in[7];

    float* acc = (float*)d_out;  // [N_NODES][64] fp32

    const size_t feat16_bytes = (size_t)N_NODES * EMBED_DIM * 2;  // 19.2 MB

    char* base = (char*)d_ws;
    size_t off = 0;
    auto take = [&](size_t bytes) {
        char* p = base + off;
        off += (bytes + 255) & ~(size_t)255;
        return p;
    };
    half4* x16           = (half4*)take(feat16_bytes);
    half4* y16           = (half4*)take(feat16_bytes);
    uint2* ecv_a         = (uint2*)take((size_t)N_EDGES * sizeof(uint2));  // 32 MB
    uint2* ecv_b         = (uint2*)take((size_t)N_EDGES * sizeof(uint2));  // 32 MB
    int*   hist          = (int*)take((size_t)NF * sizeof(int));
    int*   fine_base     = (int*)take((size_t)(NF + 1) * sizeof(int));
    int*   fine_cursor   = (int*)take((size_t)NF * sizeof(int));
    int*   coarse_cursor = (int*)take((size_t)NC * sizeof(int));
    int*   row_ptr       = (int*)take((size_t)(N_NODES + 1) * sizeof(int));
    _Float16* Wh         = (_Float16*)take((size_t)EMBED_DIM * COVER_DIM * 2);
    (void)ws_size;  // ~104 MB needed; proven available (R6-R11 ran ~104 MB)

    // ---- x0 = concat(user_emb, item_emb + cover_proj); acc = x0 ----
    {
        int n4 = N_USERS * EMBED_DIM / 4;
        build_user_x<<<(n4 + 255) / 256, 256, 0, stream>>>(
            user_emb, x16, acc, cover_W, (half4*)Wh);
    }
    {
        int grid = (N_ITEMS + 63) / 64;   // 782 blocks, 4 waves x 16 items
        build_item_x_mfma<<<grid, 256, 0, stream>>>(
            item_emb, Wh, item_cover, has_cover,
            x16 + (size_t)N_USERS * 16,
            acc + (size_t)N_USERS * EMBED_DIM);
    }

    // ---- CSR build: hist -> scan -> coarse -> fine -> exact-row sort ----
    (void)hipMemsetAsync(hist, 0, (size_t)NF * sizeof(int), stream);
    fine_hist<<<256, 256, 0, stream>>>(adj_rows, hist);
    scan_fine<<<1, 256, 0, stream>>>(hist, fine_base, fine_cursor, coarse_cursor);
    part_coarse<<<NT_A, 256, 0, stream>>>(adj_rows, adj_cols, adj_vals,
                                          coarse_cursor, ecv_a);
    part_fine<<<dim3(32, NC), 256, 0, stream>>>(ecv_a, fine_base,
                                                fine_cursor, ecv_b);
    bucket_sort<<<NF, 256, 0, stream>>>(ecv_b, fine_base, ecv_a, row_ptr);

    // ---- 3 propagation layers, acc update fused ----
    half4* x = x16;
    half4* y = y16;
    for (int l = 0; l < N_LAYERS; ++l) {
        bool last = (l == N_LAYERS - 1);
        int grid = (N_NODES + 3) / 4;   // 4 waves (rows) per 256-thread block
        spmm_csr<<<grid, 256, 0, stream>>>(
            row_ptr, ecv_a, x, y, acc,
            last ? 0.25f : 1.0f, last ? 0 : 1);
        half4* tmp = x; x = y; y = tmp;
    }
}

// Round 13
// 403.560 us; speedup vs baseline: 1.1029x; 1.0817x over previous
//
#include <hip/hip_runtime.h>

#define N_USERS   100000
#define N_ITEMS   50000
#define N_NODES   150000
#define EMBED_DIM 64
#define COVER_DIM 512
#define N_EDGES   4000000
#define N_LAYERS  3

// partition geometry
#define FINE_ROWS 128                 // rows per fine bucket
#define NF        1184                // 37*32 fine buckets (covers 151552 rows)
#define NC        37                  // coarse buckets (4096 rows each)
#define TILE_E    4096                // edges per partition tile
#define NT_A      ((N_EDGES + TILE_E - 1) / TILE_E)   // 977
#define BSORT_CAP 4096                // mean bucket 3378, sd 58 -> 12 sigma

typedef __attribute__((ext_vector_type(4))) _Float16 half4;
typedef __attribute__((ext_vector_type(8))) _Float16 f16x8;
typedef __attribute__((ext_vector_type(2))) __fp16   pk16x2;  // cvt_pkrtz result type
typedef __attribute__((ext_vector_type(4))) float    f32x4;

// ---------------------------------------------------------------------------
// x16[0:N_USERS] = fp16(user_emb) ; acc = user_emb (fp32).
// Also converts W -> Wh fp16 (first 8192 float4s of the grid).
// ---------------------------------------------------------------------------
__global__ void build_user_x(const float* __restrict__ user_emb,
                             half4* __restrict__ x16,
                             float* __restrict__ acc,
                             const float* __restrict__ W,
                             half4* __restrict__ Wh) {
    int i = blockIdx.x * blockDim.x + threadIdx.x;
    const int n4 = N_USERS * EMBED_DIM / 4;
    if (i < n4) {
        float4 v = reinterpret_cast<const float4*>(user_emb)[i];
        half4 h;
        h.x = (_Float16)v.x; h.y = (_Float16)v.y;
        h.z = (_Float16)v.z; h.w = (_Float16)v.w;
        x16[i] = h;
        reinterpret_cast<float4*>(acc)[i] = v;
    }
    if (i < EMBED_DIM * COVER_DIM / 4) {
        float4 v = reinterpret_cast<const float4*>(W)[i];
        half4 h;
        h.x = (_Float16)v.x; h.y = (_Float16)v.y;
        h.z = (_Float16)v.z; h.w = (_Float16)v.w;
        Wh[i] = h;
    }
}

// ---------------------------------------------------------------------------
// MFMA GEMM: proj = item_cover[50000x512] @ W^T[512x64]
// Block = 4 waves = 64 items. A staged through LDS in 64x64 f32 chunks.
// ---------------------------------------------------------------------------
__global__ __launch_bounds__(256) void build_item_x_mfma(
        const float* __restrict__ item_emb,
        const _Float16* __restrict__ Wh,
        const float* __restrict__ item_cover,
        const float* __restrict__ has_cover,
        half4* __restrict__ x16_items,
        float* __restrict__ acc_items) {
    __shared__ float As[64][68];                   // 17.4 KB

    const int tid  = threadIdx.x;
    const int lane = tid & 63;
    const int wid  = tid >> 6;
    const int m0   = blockIdx.x * 64;              // block's first item row
    const int mw   = m0 + wid * 16;                // wave's first item row
    const int cl   = lane & 15;
    const int kh   = lane >> 4;                    // 0..3 K-subblock

    const f16x8* bp = reinterpret_cast<const f16x8*>(Wh)
                      + (size_t)cl * (COVER_DIM / 8) + kh;

    f32x4 acc0 = {0.f, 0.f, 0.f, 0.f};
    f32x4 acc1 = {0.f, 0.f, 0.f, 0.f};
    f32x4 acc2 = {0.f, 0.f, 0.f, 0.f};
    f32x4 acc3 = {0.f, 0.f, 0.f, 0.f};

    for (int ch = 0; ch < COVER_DIM / 64; ++ch) {  // 8 chunks of K=64
#pragma unroll
        for (int it = 0; it < 4; ++it) {
            int q   = tid + it * 256;              // 0..1023
            int r   = q >> 4;                      // 0..63
            int c4  = q & 15;
            int row = m0 + r;
            if (row >= N_ITEMS) row = N_ITEMS - 1;
            float4 v = *reinterpret_cast<const float4*>(
                item_cover + (size_t)row * COVER_DIM + ch * 64 + c4 * 4);
            *reinterpret_cast<float4*>(&As[r][c4 * 4]) = v;
        }
        __syncthreads();

#pragma unroll
        for (int ks = 0; ks < 2; ++ks) {
            const float* ar = &As[wid * 16 + cl][ks * 32 + kh * 8];
            pk16x2 p0 = __builtin_amdgcn_cvt_pkrtz(ar[0], ar[1]);
            pk16x2 p1 = __builtin_amdgcn_cvt_pkrtz(ar[2], ar[3]);
            pk16x2 p2 = __builtin_amdgcn_cvt_pkrtz(ar[4], ar[5]);
            pk16x2 p3 = __builtin_amdgcn_cvt_pkrtz(ar[6], ar[7]);
            f16x8 af;
            af[0] = (_Float16)p0[0]; af[1] = (_Float16)p0[1];
            af[2] = (_Float16)p1[0]; af[3] = (_Float16)p1[1];
            af[4] = (_Float16)p2[0]; af[5] = (_Float16)p2[1];
            af[6] = (_Float16)p3[0]; af[7] = (_Float16)p3[1];

            int kq = (ch * 64 + ks * 32) >> 3;     // in f16x8 units
            f16x8 b0 = bp[kq];
            f16x8 b1 = bp[1024 + kq];
            f16x8 b2 = bp[2048 + kq];
            f16x8 b3 = bp[3072 + kq];

            acc0 = __builtin_amdgcn_mfma_f32_16x16x32_f16(af, b0, acc0, 0, 0, 0);
            acc1 = __builtin_amdgcn_mfma_f32_16x16x32_f16(af, b1, acc1, 0, 0, 0);
            acc2 = __builtin_amdgcn_mfma_f32_16x16x32_f16(af, b2, acc2, 0, 0, 0);
            acc3 = __builtin_amdgcn_mfma_f32_16x16x32_f16(af, b3, acc3, 0, 0, 0);
        }
        __syncthreads();
    }

#pragma unroll
    for (int j = 0; j < 4; ++j) {
        int item = mw + kh * 4 + j;
        if (item < N_ITEMS) {
            float hc = has_cover[item];
            const float* ep = item_emb + (size_t)item * EMBED_DIM;
            float v0 = ep[ 0 + cl] + hc * acc0[j];
            float v1 = ep[16 + cl] + hc * acc1[j];
            float v2 = ep[32 + cl] + hc * acc2[j];
            float v3 = ep[48 + cl] + hc * acc3[j];
            _Float16* xp = reinterpret_cast<_Float16*>(x16_items)
                           + (size_t)item * EMBED_DIM;
            float* cp = acc_items + (size_t)item * EMBED_DIM;
            xp[ 0 + cl] = (_Float16)v0;  cp[ 0 + cl] = v0;
            xp[16 + cl] = (_Float16)v1;  cp[16 + cl] = v1;
            xp[32 + cl] = (_Float16)v2;  cp[32 + cl] = v2;
            xp[48 + cl] = (_Float16)v3;  cp[48 + cl] = v3;
        }
    }
}

// ---------------------------------------------------------------------------
// K1: fine-bucket histogram (bucket = row >> 7), LDS-staged.
// ---------------------------------------------------------------------------
__global__ __launch_bounds__(256) void fine_hist(const int* __restrict__ rows,
                                                 int* __restrict__ hist) {
    __shared__ int h[NF];
    int tid = threadIdx.x;
    for (int i = tid; i < NF; i += 256) h[i] = 0;
    __syncthreads();
    const int n4 = N_EDGES / 4;
    int stride = gridDim.x * 256;
    for (int i = blockIdx.x * 256 + tid; i < n4; i += stride) {
        int4 r = reinterpret_cast<const int4*>(rows)[i];
        atomicAdd(&h[r.x >> 7], 1);
        atomicAdd(&h[r.y >> 7], 1);
        atomicAdd(&h[r.z >> 7], 1);
        atomicAdd(&h[r.w >> 7], 1);
    }
    __syncthreads();
    for (int i = tid; i < NF; i += 256)
        if (h[i]) atomicAdd(&hist[i], h[i]);
}

// ---------------------------------------------------------------------------
// K2: scan 1184 fine counts -> fine_base[NF+1], fine_cursor, coarse_cursor.
// ---------------------------------------------------------------------------
__global__ __launch_bounds__(256) void scan_fine(const int* __restrict__ hist,
                                                 int* __restrict__ fine_base,
                                                 int* __restrict__ fine_cursor,
                                                 int* __restrict__ coarse_cursor) {
    __shared__ int s[256];
    int tid = threadIdx.x;
    const int CH = 5;
    int lo = tid * CH;
    int loc[CH];
    int sum = 0;
#pragma unroll
    for (int i = 0; i < CH; ++i) {
        int idx = lo + i;
        int v = (idx < NF) ? hist[idx] : 0;
        loc[i] = sum;
        sum += v;
    }
    s[tid] = sum;
    __syncthreads();
    for (int off = 1; off < 256; off <<= 1) {
        int t = (tid >= off) ? s[tid - off] : 0;
        __syncthreads();
        s[tid] += t;
        __syncthreads();
    }
    int base = (tid == 0) ? 0 : s[tid - 1];
#pragma unroll
    for (int i = 0; i < CH; ++i) {
        int idx = lo + i;
        if (idx < NF) {
            int b = base + loc[i];
            fine_base[idx]   = b;
            fine_cursor[idx] = b;
        }
    }
    if (tid == 255) fine_base[NF] = s[255];
    __syncthreads();
    if (tid < NC) coarse_cursor[tid] = fine_base[tid * 32];
}

// ---------------------------------------------------------------------------
// K3: pass A — partition edges into 37 coarse buckets (4096 rows each).
// ---------------------------------------------------------------------------
__global__ __launch_bounds__(256) void part_coarse(
        const int* __restrict__ rows,
        const int* __restrict__ cols,
        const float* __restrict__ vals,
        int* __restrict__ coarse_cursor,
        uint2* __restrict__ out) {
    __shared__ unsigned s_lo[TILE_E];
    __shared__ unsigned s_hi[TILE_E];
    __shared__ unsigned char s_bin[TILE_E];
    __shared__ int s_hist[NC];
    __shared__ int s_base[NC];
    __shared__ int s_cur[NC];
    __shared__ int s_gbase[NC];

    const int tid  = threadIdx.x;
    const long long tbeg = (long long)blockIdx.x * TILE_E;
    const int cnt  = (int)((N_EDGES - tbeg) < TILE_E ? (N_EDGES - tbeg) : TILE_E);

    for (int i = tid; i < NC; i += 256) s_hist[i] = 0;
    __syncthreads();

    int r[16];
#pragma unroll
    for (int q = 0; q < 4; ++q) {
        int o = q * 1024 + tid * 4;
        if (o < cnt) {
            int4 rr = *reinterpret_cast<const int4*>(rows + tbeg + o);
            r[q*4+0] = rr.x; r[q*4+1] = rr.y; r[q*4+2] = rr.z; r[q*4+3] = rr.w;
            atomicAdd(&s_hist[rr.x >> 12], 1);
            atomicAdd(&s_hist[rr.y >> 12], 1);
            atomicAdd(&s_hist[rr.z >> 12], 1);
            atomicAdd(&s_hist[rr.w >> 12], 1);
        }
    }
    __syncthreads();

    if (tid == 0) {
        int run = 0;
        for (int b = 0; b < NC; ++b) {
            s_base[b] = run;
            s_cur[b]  = run;
            run += s_hist[b];
        }
    }
    __syncthreads();

#pragma unroll
    for (int q = 0; q < 4; ++q) {
        int o = q * 1024 + tid * 4;
        if (o < cnt) {
            int4   cc = *reinterpret_cast<const int4*>(cols + tbeg + o);
            float4 vv = *reinterpret_cast<const float4*>(vals + tbeg + o);
            int rr; int b; int pos;
            rr = r[q*4+0]; b = rr >> 12; pos = atomicAdd(&s_cur[b], 1);
            s_lo[pos] = __float_as_uint(vv.x);
            s_hi[pos] = ((unsigned)(rr & 4095) << 18) | (unsigned)cc.x;
            s_bin[pos] = (unsigned char)b;
            rr = r[q*4+1]; b = rr >> 12; pos = atomicAdd(&s_cur[b], 1);
            s_lo[pos] = __float_as_uint(vv.y);
            s_hi[pos] = ((unsigned)(rr & 4095) << 18) | (unsigned)cc.y;
            s_bin[pos] = (unsigned char)b;
            rr = r[q*4+2]; b = rr >> 12; pos = atomicAdd(&s_cur[b], 1);
            s_lo[pos] = __float_as_uint(vv.z);
            s_hi[pos] = ((unsigned)(rr & 4095) << 18) | (unsigned)cc.z;
            s_bin[pos] = (unsigned char)b;
            rr = r[q*4+3]; b = rr >> 12; pos = atomicAdd(&s_cur[b], 1);
            s_lo[pos] = __float_as_uint(vv.w);
            s_hi[pos] = ((unsigned)(rr & 4095) << 18) | (unsigned)cc.w;
            s_bin[pos] = (unsigned char)b;
        }
    }
    __syncthreads();

    if (tid < NC) {
        int c = s_hist[tid];
        s_gbase[tid] = c ? atomicAdd(&coarse_cursor[tid], c) : 0;
    }
    __syncthreads();

    for (int i = tid; i < cnt; i += 256) {
        int b = s_bin[i];
        int g = s_gbase[b] + (i - s_base[b]);
        out[g] = make_uint2(s_lo[i], s_hi[i]);
    }
}

// ---------------------------------------------------------------------------
// K4: pass B — partition each coarse region into 32 fine buckets (128 rows).
// ---------------------------------------------------------------------------
__global__ __launch_bounds__(256) void part_fine(
        const uint2* __restrict__ in,
        const int* __restrict__ fine_base,
        int* __restrict__ fine_cursor,
        uint2* __restrict__ out) {
    __shared__ unsigned s_lo[TILE_E];
    __shared__ unsigned s_hi[TILE_E];
    __shared__ unsigned char s_bin[TILE_E];
    __shared__ int s_hist[32];
    __shared__ int s_base[32];
    __shared__ int s_cur[32];
    __shared__ int s_gbase[32];

    const int tid = threadIdx.x;
    const int cb  = blockIdx.y;
    const int cbeg = fine_base[cb * 32];
    const int cend = fine_base[(cb + 1) * 32];
    const int tbeg = cbeg + blockIdx.x * TILE_E;
    if (tbeg >= cend) return;
    const int cnt = (cend - tbeg) < TILE_E ? (cend - tbeg) : TILE_E;

    if (tid < 32) s_hist[tid] = 0;
    __syncthreads();

    unsigned elo[16], ehi[16];
#pragma unroll
    for (int j = 0; j < 16; ++j) {
        int o = tid + j * 256;
        if (o < cnt) {
            uint2 e = in[tbeg + o];
            elo[j] = e.x; ehi[j] = e.y;
            atomicAdd(&s_hist[ehi[j] >> 25], 1);
        }
    }
    __syncthreads();

    if (tid == 0) {
        int run = 0;
        for (int b = 0; b < 32; ++b) {
            s_base[b] = run;
            s_cur[b]  = run;
            run += s_hist[b];
        }
    }
    __syncthreads();

#pragma unroll
    for (int j = 0; j < 16; ++j) {
        int o = tid + j * 256;
        if (o < cnt) {
            int b = ehi[j] >> 25;
            int pos = atomicAdd(&s_cur[b], 1);
            s_lo[pos]  = elo[j];
            s_hi[pos]  = ehi[j] & 0x1FFFFFFu;
            s_bin[pos] = (unsigned char)b;
        }
    }
    __syncthreads();

    if (tid < 32) {
        int c = s_hist[tid];
        s_gbase[tid] = c ? atomicAdd(&fine_cursor[cb * 32 + tid], c) : 0;
    }
    __syncthreads();

    for (int i = tid; i < cnt; i += 256) {
        int b = s_bin[i];
        int g = s_gbase[b] + (i - s_base[b]);
        out[g] = make_uint2(s_lo[i], s_hi[i]);
    }
}

// ---------------------------------------------------------------------------
// K5: per-bucket exact-row counting sort (LDS) -> CSR order + row_ptr.
// ---------------------------------------------------------------------------
__global__ __launch_bounds__(256) void bucket_sort(
        const uint2* __restrict__ in,
        const int* __restrict__ fine_base,
        uint2* __restrict__ out,
        int* __restrict__ row_ptr) {
    __shared__ unsigned s_lo[BSORT_CAP];
    __shared__ unsigned s_hi[BSORT_CAP];
    __shared__ int s_hist[FINE_ROWS];
    __shared__ int s_scan[FINE_ROWS];
    __shared__ int s_cur[FINE_ROWS];

    const int f   = blockIdx.x;
    const int tid = threadIdx.x;
    const int beg = fine_base[f];
    const int end = fine_base[f + 1];
    const int cnt = end - beg;

    if (tid < FINE_ROWS) s_hist[tid] = 0;
    __syncthreads();

    unsigned elo[16], ehi[16];
#pragma unroll
    for (int j = 0; j < 16; ++j) {
        int o = tid + j * 256;
        if (o < cnt) {
            uint2 e = in[beg + o];
            elo[j] = e.x; ehi[j] = e.y;
            atomicAdd(&s_hist[ehi[j] >> 18], 1);
        }
    }
    __syncthreads();

    if (tid < FINE_ROWS) s_scan[tid] = s_hist[tid];
    __syncthreads();
    for (int off = 1; off < FINE_ROWS; off <<= 1) {
        int v = 0;
        if (tid < FINE_ROWS && tid >= off) v = s_scan[tid - off];
        __syncthreads();
        if (tid < FINE_ROWS) s_scan[tid] += v;
        __syncthreads();
    }
    if (tid < FINE_ROWS) {
        int excl = s_scan[tid] - s_hist[tid];
        s_cur[tid] = excl;
        int grow = f * FINE_ROWS + tid;
        if (grow <= N_NODES) row_ptr[grow] = beg + excl;
    }
    __syncthreads();

#pragma unroll
    for (int j = 0; j < 16; ++j) {
        int o = tid + j * 256;
        if (o < cnt) {
            int r = (int)(ehi[j] >> 18);
            int pos = atomicAdd(&s_cur[r], 1);
            s_lo[pos] = elo[j];
            s_hi[pos] = ehi[j];
        }
    }
    __syncthreads();

    for (int i = tid; i < cnt; i += 256)
        out[beg + i] = make_uint2(s_lo[i], s_hi[i]);
}

// ---------------------------------------------------------------------------
// K6: CSR SpMM, one wave per row; EIGHTH-wave (8 lanes x 16B) per edge,
// 2 edges per group in flight (stride 16) -> one load instruction serves
// 8 edges x 128B, 16 independent gathers per wave.
// fp16 gathers, fp32 accumulate. Fused acc update.
// ---------------------------------------------------------------------------
__global__ __launch_bounds__(256) void spmm_csr(const int* __restrict__ row_ptr,
                                                const uint2* __restrict__ ecv,
                                                const half4* __restrict__ x16_,
                                                half4* __restrict__ y16_,
                                                float* __restrict__ acc,
                                                float scale, int write_y) {
    const f16x8* x16 = reinterpret_cast<const f16x8*>(x16_);
    f16x8* y16 = reinterpret_cast<f16x8*>(y16_);

    int wave = (int)((blockIdx.x * blockDim.x + threadIdx.x) >> 6);
    int lane = threadIdx.x & 63;
    if (wave >= N_NODES) return;
    int row  = wave;
    int beg  = row_ptr[row];
    int end  = row_ptr[row + 1];
    int esub = lane >> 3;     // 0..7 edge-group
    int p    = lane & 7;      // which f16x8 (16B) of the 128B row

    float a[8] = {0.f, 0.f, 0.f, 0.f, 0.f, 0.f, 0.f, 0.f};
    int j = beg + esub * 2;
    for (; j + 2 <= end; j += 16) {
        uint2 cv0 = ecv[j];
        uint2 cv1 = ecv[j + 1];
        int c0 = (int)(cv0.y & 0x3FFFFu);
        int c1 = (int)(cv1.y & 0x3FFFFu);
        f16x8 xv0 = x16[(size_t)c0 * 8 + p];
        f16x8 xv1 = x16[(size_t)c1 * 8 + p];
        float v0 = __uint_as_float(cv0.x);
        float v1 = __uint_as_float(cv1.x);
#pragma unroll
        for (int q = 0; q < 8; ++q) a[q] += v0 * (float)xv0[q];
#pragma unroll
        for (int q = 0; q < 8; ++q) a[q] += v1 * (float)xv1[q];
    }
    if (j < end) {
        uint2 cv = ecv[j];
        int c = (int)(cv.y & 0x3FFFFu);
        f16x8 xv = x16[(size_t)c * 8 + p];
        float v = __uint_as_float(cv.x);
#pragma unroll
        for (int q = 0; q < 8; ++q) a[q] += v * (float)xv[q];
    }
    // reduce the 8 esub groups (lanes differing in bits 3,4,5)
#pragma unroll
    for (int m = 8; m <= 32; m <<= 1) {
#pragma unroll
        for (int q = 0; q < 8; ++q) a[q] += __shfl_xor(a[q], m, 64);
    }
    if (esub == 0) {          // lanes 0..7 hold the row result
        if (write_y) {
            f16x8 h;
#pragma unroll
            for (int q = 0; q < 8; ++q) h[q] = (_Float16)a[q];
            y16[(size_t)row * 8 + p] = h;
        }
        // acc: dims p*8..p*8+7 = two float4s at idx row*16 + p*2 (+1)
        size_t ai = (size_t)row * 16 + p * 2;
        float4 av0 = reinterpret_cast<float4*>(acc)[ai];
        float4 av1 = reinterpret_cast<float4*>(acc)[ai + 1];
        av0.x = (av0.x + a[0]) * scale;
        av0.y = (av0.y + a[1]) * scale;
        av0.z = (av0.z + a[2]) * scale;
        av0.w = (av0.w + a[3]) * scale;
        av1.x = (av1.x + a[4]) * scale;
        av1.y = (av1.y + a[5]) * scale;
        av1.z = (av1.z + a[6]) * scale;
        av1.w = (av1.w + a[7]) * scale;
        reinterpret_cast<float4*>(acc)[ai]     = av0;
        reinterpret_cast<float4*>(acc)[ai + 1] = av1;
    }
}

extern "C" void kernel_launch(void* const* d_in, const int* in_sizes, int n_in,
                              void* d_out, int out_size, void* d_ws, size_t ws_size,
                              hipStream_t stream) {
    const float* user_emb   = (const float*)d_in[0];
    const float* item_emb   = (const float*)d_in[1];
    const float* cover_W    = (const float*)d_in[2];
    const float* item_cover = (const float*)d_in[3];
    const float* has_cover  = (const float*)d_in[4];
    const float* adj_vals   = (const float*)d_in[5];
    const int*   adj_rows   = (const int*)d_in[6];
    const int*   adj_cols   = (const int*)d_in[7];

    float* acc = (float*)d_out;  // [N_NODES][64] fp32

    const size_t feat16_bytes = (size_t)N_NODES * EMBED_DIM * 2;  // 19.2 MB

    char* base = (char*)d_ws;
    size_t off = 0;
    auto take = [&](size_t bytes) {
        char* p = base + off;
        off += (bytes + 255) & ~(size_t)255;
        return p;
    };
    half4* x16           = (half4*)take(feat16_bytes);
    half4* y16           = (half4*)take(feat16_bytes);
    uint2* ecv_a         = (uint2*)take((size_t)N_EDGES * sizeof(uint2));  // 32 MB
    uint2* ecv_b         = (uint2*)take((size_t)N_EDGES * sizeof(uint2));  // 32 MB
    int*   hist          = (int*)take((size_t)NF * sizeof(int));
    int*   fine_base     = (int*)take((size_t)(NF + 1) * sizeof(int));
    int*   fine_cursor   = (int*)take((size_t)NF * sizeof(int));
    int*   coarse_cursor = (int*)take((size_t)NC * sizeof(int));
    int*   row_ptr       = (int*)take((size_t)(N_NODES + 1) * sizeof(int));
    _Float16* Wh         = (_Float16*)take((size_t)EMBED_DIM * COVER_DIM * 2);
    (void)ws_size;  // ~104 MB needed; proven available (R6-R12 ran ~104 MB)

    // ---- x0 = concat(user_emb, item_emb + cover_proj); acc = x0 ----
    {
        int n4 = N_USERS * EMBED_DIM / 4;
        build_user_x<<<(n4 + 255) / 256, 256, 0, stream>>>(
            user_emb, x16, acc, cover_W, (half4*)Wh);
    }
    {
        int grid = (N_ITEMS + 63) / 64;   // 782 blocks, 4 waves x 16 items
        build_item_x_mfma<<<grid, 256, 0, stream>>>(
            item_emb, Wh, item_cover, has_cover,
            x16 + (size_t)N_USERS * 16,
            acc + (size_t)N_USERS * EMBED_DIM);
    }

    // ---- CSR build: hist -> scan -> coarse -> fine -> exact-row sort ----
    (void)hipMemsetAsync(hist, 0, (size_t)NF * sizeof(int), stream);
    fine_hist<<<256, 256, 0, stream>>>(adj_rows, hist);
    scan_fine<<<1, 256, 0, stream>>>(hist, fine_base, fine_cursor, coarse_cursor);
    part_coarse<<<NT_A, 256, 0, stream>>>(adj_rows, adj_cols, adj_vals,
                                          coarse_cursor, ecv_a);
    part_fine<<<dim3(32, NC), 256, 0, stream>>>(ecv_a, fine_base,
                                                fine_cursor, ecv_b);
    bucket_sort<<<NF, 256, 0, stream>>>(ecv_b, fine_base, ecv_a, row_ptr);

    // ---- 3 propagation layers, acc update fused ----
    half4* x = x16;
    half4* y = y16;
    for (int l = 0; l < N_LAYERS; ++l) {
        bool last = (l == N_LAYERS - 1);
        int grid = (N_NODES + 3) / 4;   // 4 waves (rows) per 256-thread block
        spmm_csr<<<grid, 256, 0, stream>>>(
            row_ptr, ecv_a, x, y, acc,
            last ? 0.25f : 1.0f, last ? 0 : 1);
        half4* tmp = x; x = y; y = tmp;
    }
}

// Round 14
// 403.473 us; speedup vs baseline: 1.1031x; 1.0002x over previous
//
#include <hip/hip_runtime.h>

#define N_USERS   100000
#define N_ITEMS   50000
#define N_NODES   150000
#define EMBED_DIM 64
#define COVER_DIM 512
#define N_EDGES   4000000
#define N_LAYERS  3

// partition geometry
#define FINE_ROWS 128                 // rows per fine bucket
#define NF        1184                // 37*32 fine buckets (covers 151552 rows)
#define NC        37                  // coarse buckets (4096 rows each)
#define TILE_E    4096                // edges per partition tile
#define NT_A      ((N_EDGES + TILE_E - 1) / TILE_E)   // 977
#define BSORT_CAP 4096                // mean bucket 3378, sd 58 -> 12 sigma

typedef __attribute__((ext_vector_type(4))) _Float16 half4;
typedef __attribute__((ext_vector_type(8))) _Float16 f16x8;
typedef __attribute__((ext_vector_type(2))) __fp16   pk16x2;  // cvt_pkrtz result type
typedef __attribute__((ext_vector_type(4))) float    f32x4;

// ---------------------------------------------------------------------------
// x16[0:N_USERS] = fp16(user_emb) ; acc = user_emb (fp32).
// Also converts W -> Wh fp16 (first 8192 float4s of the grid).
// ---------------------------------------------------------------------------
__global__ void build_user_x(const float* __restrict__ user_emb,
                             half4* __restrict__ x16,
                             float* __restrict__ acc,
                             const float* __restrict__ W,
                             half4* __restrict__ Wh) {
    int i = blockIdx.x * blockDim.x + threadIdx.x;
    const int n4 = N_USERS * EMBED_DIM / 4;
    if (i < n4) {
        float4 v = reinterpret_cast<const float4*>(user_emb)[i];
        half4 h;
        h.x = (_Float16)v.x; h.y = (_Float16)v.y;
        h.z = (_Float16)v.z; h.w = (_Float16)v.w;
        x16[i] = h;
        reinterpret_cast<float4*>(acc)[i] = v;
    }
    if (i < EMBED_DIM * COVER_DIM / 4) {
        float4 v = reinterpret_cast<const float4*>(W)[i];
        half4 h;
        h.x = (_Float16)v.x; h.y = (_Float16)v.y;
        h.z = (_Float16)v.z; h.w = (_Float16)v.w;
        Wh[i] = h;
    }
}

// ---------------------------------------------------------------------------
// MFMA GEMM: proj = item_cover[50000x512] @ W^T[512x64]
// Block = 4 waves = 64 items. A staged through LDS in 64x64 f32 chunks.
// ---------------------------------------------------------------------------
__global__ __launch_bounds__(256) void build_item_x_mfma(
        const float* __restrict__ item_emb,
        const _Float16* __restrict__ Wh,
        const float* __restrict__ item_cover,
        const float* __restrict__ has_cover,
        half4* __restrict__ x16_items,
        float* __restrict__ acc_items) {
    __shared__ float As[64][68];                   // 17.4 KB

    const int tid  = threadIdx.x;
    const int lane = tid & 63;
    const int wid  = tid >> 6;
    const int m0   = blockIdx.x * 64;              // block's first item row
    const int mw   = m0 + wid * 16;                // wave's first item row
    const int cl   = lane & 15;
    const int kh   = lane >> 4;                    // 0..3 K-subblock

    const f16x8* bp = reinterpret_cast<const f16x8*>(Wh)
                      + (size_t)cl * (COVER_DIM / 8) + kh;

    f32x4 acc0 = {0.f, 0.f, 0.f, 0.f};
    f32x4 acc1 = {0.f, 0.f, 0.f, 0.f};
    f32x4 acc2 = {0.f, 0.f, 0.f, 0.f};
    f32x4 acc3 = {0.f, 0.f, 0.f, 0.f};

    for (int ch = 0; ch < COVER_DIM / 64; ++ch) {  // 8 chunks of K=64
#pragma unroll
        for (int it = 0; it < 4; ++it) {
            int q   = tid + it * 256;              // 0..1023
            int r   = q >> 4;                      // 0..63
            int c4  = q & 15;
            int row = m0 + r;
            if (row >= N_ITEMS) row = N_ITEMS - 1;
            float4 v = *reinterpret_cast<const float4*>(
                item_cover + (size_t)row * COVER_DIM + ch * 64 + c4 * 4);
            *reinterpret_cast<float4*>(&As[r][c4 * 4]) = v;
        }
        __syncthreads();

#pragma unroll
        for (int ks = 0; ks < 2; ++ks) {
            const float* ar = &As[wid * 16 + cl][ks * 32 + kh * 8];
            pk16x2 p0 = __builtin_amdgcn_cvt_pkrtz(ar[0], ar[1]);
            pk16x2 p1 = __builtin_amdgcn_cvt_pkrtz(ar[2], ar[3]);
            pk16x2 p2 = __builtin_amdgcn_cvt_pkrtz(ar[4], ar[5]);
            pk16x2 p3 = __builtin_amdgcn_cvt_pkrtz(ar[6], ar[7]);
            f16x8 af;
            af[0] = (_Float16)p0[0]; af[1] = (_Float16)p0[1];
            af[2] = (_Float16)p1[0]; af[3] = (_Float16)p1[1];
            af[4] = (_Float16)p2[0]; af[5] = (_Float16)p2[1];
            af[6] = (_Float16)p3[0]; af[7] = (_Float16)p3[1];

            int kq = (ch * 64 + ks * 32) >> 3;     // in f16x8 units
            f16x8 b0 = bp[kq];
            f16x8 b1 = bp[1024 + kq];
            f16x8 b2 = bp[2048 + kq];
            f16x8 b3 = bp[3072 + kq];

            acc0 = __builtin_amdgcn_mfma_f32_16x16x32_f16(af, b0, acc0, 0, 0, 0);
            acc1 = __builtin_amdgcn_mfma_f32_16x16x32_f16(af, b1, acc1, 0, 0, 0);
            acc2 = __builtin_amdgcn_mfma_f32_16x16x32_f16(af, b2, acc2, 0, 0, 0);
            acc3 = __builtin_amdgcn_mfma_f32_16x16x32_f16(af, b3, acc3, 0, 0, 0);
        }
        __syncthreads();
    }

#pragma unroll
    for (int j = 0; j < 4; ++j) {
        int item = mw + kh * 4 + j;
        if (item < N_ITEMS) {
            float hc = has_cover[item];
            const float* ep = item_emb + (size_t)item * EMBED_DIM;
            float v0 = ep[ 0 + cl] + hc * acc0[j];
            float v1 = ep[16 + cl] + hc * acc1[j];
            float v2 = ep[32 + cl] + hc * acc2[j];
            float v3 = ep[48 + cl] + hc * acc3[j];
            _Float16* xp = reinterpret_cast<_Float16*>(x16_items)
                           + (size_t)item * EMBED_DIM;
            float* cp = acc_items + (size_t)item * EMBED_DIM;
            xp[ 0 + cl] = (_Float16)v0;  cp[ 0 + cl] = v0;
            xp[16 + cl] = (_Float16)v1;  cp[16 + cl] = v1;
            xp[32 + cl] = (_Float16)v2;  cp[32 + cl] = v2;
            xp[48 + cl] = (_Float16)v3;  cp[48 + cl] = v3;
        }
    }
}

// ---------------------------------------------------------------------------
// K1: fine-bucket histogram (bucket = row >> 7), LDS-staged.
// ---------------------------------------------------------------------------
__global__ __launch_bounds__(256) void fine_hist(const int* __restrict__ rows,
                                                 int* __restrict__ hist) {
    __shared__ int h[NF];
    int tid = threadIdx.x;
    for (int i = tid; i < NF; i += 256) h[i] = 0;
    __syncthreads();
    const int n4 = N_EDGES / 4;
    int stride = gridDim.x * 256;
    for (int i = blockIdx.x * 256 + tid; i < n4; i += stride) {
        int4 r = reinterpret_cast<const int4*>(rows)[i];
        atomicAdd(&h[r.x >> 7], 1);
        atomicAdd(&h[r.y >> 7], 1);
        atomicAdd(&h[r.z >> 7], 1);
        atomicAdd(&h[r.w >> 7], 1);
    }
    __syncthreads();
    for (int i = tid; i < NF; i += 256)
        if (h[i]) atomicAdd(&hist[i], h[i]);
}

// ---------------------------------------------------------------------------
// K2: scan 1184 fine counts -> fine_base[NF+1], fine_cursor, coarse_cursor.
// ---------------------------------------------------------------------------
__global__ __launch_bounds__(256) void scan_fine(const int* __restrict__ hist,
                                                 int* __restrict__ fine_base,
                                                 int* __restrict__ fine_cursor,
                                                 int* __restrict__ coarse_cursor) {
    __shared__ int s[256];
    int tid = threadIdx.x;
    const int CH = 5;
    int lo = tid * CH;
    int loc[CH];
    int sum = 0;
#pragma unroll
    for (int i = 0; i < CH; ++i) {
        int idx = lo + i;
        int v = (idx < NF) ? hist[idx] : 0;
        loc[i] = sum;
        sum += v;
    }
    s[tid] = sum;
    __syncthreads();
    for (int off = 1; off < 256; off <<= 1) {
        int t = (tid >= off) ? s[tid - off] : 0;
        __syncthreads();
        s[tid] += t;
        __syncthreads();
    }
    int base = (tid == 0) ? 0 : s[tid - 1];
#pragma unroll
    for (int i = 0; i < CH; ++i) {
        int idx = lo + i;
        if (idx < NF) {
            int b = base + loc[i];
            fine_base[idx]   = b;
            fine_cursor[idx] = b;
        }
    }
    if (tid == 255) fine_base[NF] = s[255];
    __syncthreads();
    if (tid < NC) coarse_cursor[tid] = fine_base[tid * 32];
}

// ---------------------------------------------------------------------------
// K3: pass A — partition edges into 37 coarse buckets (4096 rows each).
// ---------------------------------------------------------------------------
__global__ __launch_bounds__(256) void part_coarse(
        const int* __restrict__ rows,
        const int* __restrict__ cols,
        const float* __restrict__ vals,
        int* __restrict__ coarse_cursor,
        uint2* __restrict__ out) {
    __shared__ unsigned s_lo[TILE_E];
    __shared__ unsigned s_hi[TILE_E];
    __shared__ unsigned char s_bin[TILE_E];
    __shared__ int s_hist[NC];
    __shared__ int s_base[NC];
    __shared__ int s_cur[NC];
    __shared__ int s_gbase[NC];

    const int tid  = threadIdx.x;
    const long long tbeg = (long long)blockIdx.x * TILE_E;
    const int cnt  = (int)((N_EDGES - tbeg) < TILE_E ? (N_EDGES - tbeg) : TILE_E);

    for (int i = tid; i < NC; i += 256) s_hist[i] = 0;
    __syncthreads();

    int r[16];
#pragma unroll
    for (int q = 0; q < 4; ++q) {
        int o = q * 1024 + tid * 4;
        if (o < cnt) {
            int4 rr = *reinterpret_cast<const int4*>(rows + tbeg + o);
            r[q*4+0] = rr.x; r[q*4+1] = rr.y; r[q*4+2] = rr.z; r[q*4+3] = rr.w;
            atomicAdd(&s_hist[rr.x >> 12], 1);
            atomicAdd(&s_hist[rr.y >> 12], 1);
            atomicAdd(&s_hist[rr.z >> 12], 1);
            atomicAdd(&s_hist[rr.w >> 12], 1);
        }
    }
    __syncthreads();

    if (tid == 0) {
        int run = 0;
        for (int b = 0; b < NC; ++b) {
            s_base[b] = run;
            s_cur[b]  = run;
            run += s_hist[b];
        }
    }
    __syncthreads();

#pragma unroll
    for (int q = 0; q < 4; ++q) {
        int o = q * 1024 + tid * 4;
        if (o < cnt) {
            int4   cc = *reinterpret_cast<const int4*>(cols + tbeg + o);
            float4 vv = *reinterpret_cast<const float4*>(vals + tbeg + o);
            int rr; int b; int pos;
            rr = r[q*4+0]; b = rr >> 12; pos = atomicAdd(&s_cur[b], 1);
            s_lo[pos] = __float_as_uint(vv.x);
            s_hi[pos] = ((unsigned)(rr & 4095) << 18) | (unsigned)cc.x;
            s_bin[pos] = (unsigned char)b;
            rr = r[q*4+1]; b = rr >> 12; pos = atomicAdd(&s_cur[b], 1);
            s_lo[pos] = __float_as_uint(vv.y);
            s_hi[pos] = ((unsigned)(rr & 4095) << 18) | (unsigned)cc.y;
            s_bin[pos] = (unsigned char)b;
            rr = r[q*4+2]; b = rr >> 12; pos = atomicAdd(&s_cur[b], 1);
            s_lo[pos] = __float_as_uint(vv.z);
            s_hi[pos] = ((unsigned)(rr & 4095) << 18) | (unsigned)cc.z;
            s_bin[pos] = (unsigned char)b;
            rr = r[q*4+3]; b = rr >> 12; pos = atomicAdd(&s_cur[b], 1);
            s_lo[pos] = __float_as_uint(vv.w);
            s_hi[pos] = ((unsigned)(rr & 4095) << 18) | (unsigned)cc.w;
            s_bin[pos] = (unsigned char)b;
        }
    }
    __syncthreads();

    if (tid < NC) {
        int c = s_hist[tid];
        s_gbase[tid] = c ? atomicAdd(&coarse_cursor[tid], c) : 0;
    }
    __syncthreads();

    for (int i = tid; i < cnt; i += 256) {
        int b = s_bin[i];
        int g = s_gbase[b] + (i - s_base[b]);
        out[g] = make_uint2(s_lo[i], s_hi[i]);
    }
}

// ---------------------------------------------------------------------------
// K4: pass B — partition each coarse region into 32 fine buckets (128 rows).
// ---------------------------------------------------------------------------
__global__ __launch_bounds__(256) void part_fine(
        const uint2* __restrict__ in,
        const int* __restrict__ fine_base,
        int* __restrict__ fine_cursor,
        uint2* __restrict__ out) {
    __shared__ unsigned s_lo[TILE_E];
    __shared__ unsigned s_hi[TILE_E];
    __shared__ unsigned char s_bin[TILE_E];
    __shared__ int s_hist[32];
    __shared__ int s_base[32];
    __shared__ int s_cur[32];
    __shared__ int s_gbase[32];

    const int tid = threadIdx.x;
    const int cb  = blockIdx.y;
    const int cbeg = fine_base[cb * 32];
    const int cend = fine_base[(cb + 1) * 32];
    const int tbeg = cbeg + blockIdx.x * TILE_E;
    if (tbeg >= cend) return;
    const int cnt = (cend - tbeg) < TILE_E ? (cend - tbeg) : TILE_E;

    if (tid < 32) s_hist[tid] = 0;
    __syncthreads();

    unsigned elo[16], ehi[16];
#pragma unroll
    for (int j = 0; j < 16; ++j) {
        int o = tid + j * 256;
        if (o < cnt) {
            uint2 e = in[tbeg + o];
            elo[j] = e.x; ehi[j] = e.y;
            atomicAdd(&s_hist[ehi[j] >> 25], 1);
        }
    }
    __syncthreads();

    if (tid == 0) {
        int run = 0;
        for (int b = 0; b < 32; ++b) {
            s_base[b] = run;
            s_cur[b]  = run;
            run += s_hist[b];
        }
    }
    __syncthreads();

#pragma unroll
    for (int j = 0; j < 16; ++j) {
        int o = tid + j * 256;
        if (o < cnt) {
            int b = ehi[j] >> 25;
            int pos = atomicAdd(&s_cur[b], 1);
            s_lo[pos]  = elo[j];
            s_hi[pos]  = ehi[j] & 0x1FFFFFFu;
            s_bin[pos] = (unsigned char)b;
        }
    }
    __syncthreads();

    if (tid < 32) {
        int c = s_hist[tid];
        s_gbase[tid] = c ? atomicAdd(&fine_cursor[cb * 32 + tid], c) : 0;
    }
    __syncthreads();

    for (int i = tid; i < cnt; i += 256) {
        int b = s_bin[i];
        int g = s_gbase[b] + (i - s_base[b]);
        out[g] = make_uint2(s_lo[i], s_hi[i]);
    }
}

// ---------------------------------------------------------------------------
// K5: per-bucket exact-row counting sort (LDS) -> CSR order + row_ptr.
// ---------------------------------------------------------------------------
__global__ __launch_bounds__(256) void bucket_sort(
        const uint2* __restrict__ in,
        const int* __restrict__ fine_base,
        uint2* __restrict__ out,
        int* __restrict__ row_ptr) {
    __shared__ unsigned s_lo[BSORT_CAP];
    __shared__ unsigned s_hi[BSORT_CAP];
    __shared__ int s_hist[FINE_ROWS];
    __shared__ int s_scan[FINE_ROWS];
    __shared__ int s_cur[FINE_ROWS];

    const int f   = blockIdx.x;
    const int tid = threadIdx.x;
    const int beg = fine_base[f];
    const int end = fine_base[f + 1];
    const int cnt = end - beg;

    if (tid < FINE_ROWS) s_hist[tid] = 0;
    __syncthreads();

    unsigned elo[16], ehi[16];
#pragma unroll
    for (int j = 0; j < 16; ++j) {
        int o = tid + j * 256;
        if (o < cnt) {
            uint2 e = in[beg + o];
            elo[j] = e.x; ehi[j] = e.y;
            atomicAdd(&s_hist[ehi[j] >> 18], 1);
        }
    }
    __syncthreads();

    if (tid < FINE_ROWS) s_scan[tid] = s_hist[tid];
    __syncthreads();
    for (int off = 1; off < FINE_ROWS; off <<= 1) {
        int v = 0;
        if (tid < FINE_ROWS && tid >= off) v = s_scan[tid - off];
        __syncthreads();
        if (tid < FINE_ROWS) s_scan[tid] += v;
        __syncthreads();
    }
    if (tid < FINE_ROWS) {
        int excl = s_scan[tid] - s_hist[tid];
        s_cur[tid] = excl;
        int grow = f * FINE_ROWS + tid;
        if (grow <= N_NODES) row_ptr[grow] = beg + excl;
    }
    __syncthreads();

#pragma unroll
    for (int j = 0; j < 16; ++j) {
        int o = tid + j * 256;
        if (o < cnt) {
            int r = (int)(ehi[j] >> 18);
            int pos = atomicAdd(&s_cur[r], 1);
            s_lo[pos] = elo[j];
            s_hi[pos] = ehi[j];
        }
    }
    __syncthreads();

    for (int i = tid; i < cnt; i += 256)
        out[beg + i] = make_uint2(s_lo[i], s_hi[i]);
}

// ---------------------------------------------------------------------------
// K6: CSR SpMM, one wave per row; eighth-wave (8 lanes x 16B) per edge,
// 2 edges per group in flight; ONE uint4 load fetches both ecv entries.
// fp16 gathers, fp32 accumulate. Fused acc update.
// ---------------------------------------------------------------------------
__global__ __launch_bounds__(256) void spmm_csr(const int* __restrict__ row_ptr,
                                                const uint2* __restrict__ ecv,
                                                const half4* __restrict__ x16_,
                                                half4* __restrict__ y16_,
                                                float* __restrict__ acc,
                                                float scale, int write_y) {
    const f16x8* x16 = reinterpret_cast<const f16x8*>(x16_);
    f16x8* y16 = reinterpret_cast<f16x8*>(y16_);

    int wave = (int)((blockIdx.x * blockDim.x + threadIdx.x) >> 6);
    int lane = threadIdx.x & 63;
    if (wave >= N_NODES) return;
    int row  = wave;
    int beg  = row_ptr[row];
    int end  = row_ptr[row + 1];
    int esub = lane >> 3;     // 0..7 edge-group
    int p    = lane & 7;      // which f16x8 (16B) of the 128B row

    float a[8] = {0.f, 0.f, 0.f, 0.f, 0.f, 0.f, 0.f, 0.f};
    int j = beg + esub * 2;
    for (; j + 2 <= end; j += 16) {
        // one 16B load = both edges' (val, col) entries (ecv is 8B-aligned)
        uint4 cv01 = *reinterpret_cast<const uint4*>(ecv + j);
        int c0 = (int)(cv01.y & 0x3FFFFu);
        int c1 = (int)(cv01.w & 0x3FFFFu);
        f16x8 xv0 = x16[(size_t)c0 * 8 + p];
        f16x8 xv1 = x16[(size_t)c1 * 8 + p];
        float v0 = __uint_as_float(cv01.x);
        float v1 = __uint_as_float(cv01.z);
#pragma unroll
        for (int q = 0; q < 8; ++q) a[q] += v0 * (float)xv0[q];
#pragma unroll
        for (int q = 0; q < 8; ++q) a[q] += v1 * (float)xv1[q];
    }
    if (j < end) {
        uint2 cv = ecv[j];
        int c = (int)(cv.y & 0x3FFFFu);
        f16x8 xv = x16[(size_t)c * 8 + p];
        float v = __uint_as_float(cv.x);
#pragma unroll
        for (int q = 0; q < 8; ++q) a[q] += v * (float)xv[q];
    }
    // reduce the 8 esub groups (lanes differing in bits 3,4,5)
#pragma unroll
    for (int m = 8; m <= 32; m <<= 1) {
#pragma unroll
        for (int q = 0; q < 8; ++q) a[q] += __shfl_xor(a[q], m, 64);
    }
    if (esub == 0) {          // lanes 0..7 hold the row result
        if (write_y) {
            f16x8 h;
#pragma unroll
            for (int q = 0; q < 8; ++q) h[q] = (_Float16)a[q];
            y16[(size_t)row * 8 + p] = h;
        }
        size_t ai = (size_t)row * 16 + p * 2;
        float4 av0 = reinterpret_cast<float4*>(acc)[ai];
        float4 av1 = reinterpret_cast<float4*>(acc)[ai + 1];
        av0.x = (av0.x + a[0]) * scale;
        av0.y = (av0.y + a[1]) * scale;
        av0.z = (av0.z + a[2]) * scale;
        av0.w = (av0.w + a[3]) * scale;
        av1.x = (av1.x + a[4]) * scale;
        av1.y = (av1.y + a[5]) * scale;
        av1.z = (av1.z + a[6]) * scale;
        av1.w = (av1.w + a[7]) * scale;
        reinterpret_cast<float4*>(acc)[ai]     = av0;
        reinterpret_cast<float4*>(acc)[ai + 1] = av1;
    }
}

extern "C" void kernel_launch(void* const* d_in, const int* in_sizes, int n_in,
                              void* d_out, int out_size, void* d_ws, size_t ws_size,
                              hipStream_t stream) {
    const float* user_emb   = (const float*)d_in[0];
    const float* item_emb   = (const float*)d_in[1];
    const float* cover_W    = (const float*)d_in[2];
    const float* item_cover = (const float*)d_in[3];
    const float* has_cover  = (const float*)d_in[4];
    const float* adj_vals   = (const float*)d_in[5];
    const int*   adj_rows   = (const int*)d_in[6];
    const int*   adj_cols   = (const int*)d_in[7];

    float* acc = (float*)d_out;  // [N_NODES][64] fp32

    const size_t feat16_bytes = (size_t)N_NODES * EMBED_DIM * 2;  // 19.2 MB

    char* base = (char*)d_ws;
    size_t off = 0;
    auto take = [&](size_t bytes) {
        char* p = base + off;
        off += (bytes + 255) & ~(size_t)255;
        return p;
    };
    half4* x16           = (half4*)take(feat16_bytes);
    half4* y16           = (half4*)take(feat16_bytes);
    uint2* ecv_a         = (uint2*)take((size_t)N_EDGES * sizeof(uint2));  // 32 MB
    uint2* ecv_b         = (uint2*)take((size_t)N_EDGES * sizeof(uint2));  // 32 MB
    int*   hist          = (int*)take((size_t)NF * sizeof(int));
    int*   fine_base     = (int*)take((size_t)(NF + 1) * sizeof(int));
    int*   fine_cursor   = (int*)take((size_t)NF * sizeof(int));
    int*   coarse_cursor = (int*)take((size_t)NC * sizeof(int));
    int*   row_ptr       = (int*)take((size_t)(N_NODES + 1) * sizeof(int));
    _Float16* Wh         = (_Float16*)take((size_t)EMBED_DIM * COVER_DIM * 2);
    (void)ws_size;  // ~104 MB needed; proven available (R6-R13 ran ~104 MB)

    // ---- x0 = concat(user_emb, item_emb + cover_proj); acc = x0 ----
    {
        int n4 = N_USERS * EMBED_DIM / 4;
        build_user_x<<<(n4 + 255) / 256, 256, 0, stream>>>(
            user_emb, x16, acc, cover_W, (half4*)Wh);
    }
    {
        int grid = (N_ITEMS + 63) / 64;   // 782 blocks, 4 waves x 16 items
        build_item_x_mfma<<<grid, 256, 0, stream>>>(
            item_emb, Wh, item_cover, has_cover,
            x16 + (size_t)N_USERS * 16,
            acc + (size_t)N_USERS * EMBED_DIM);
    }

    // ---- CSR build: hist -> scan -> coarse -> fine -> exact-row sort ----
    (void)hipMemsetAsync(hist, 0, (size_t)NF * sizeof(int), stream);
    fine_hist<<<256, 256, 0, stream>>>(adj_rows, hist);
    scan_fine<<<1, 256, 0, stream>>>(hist, fine_base, fine_cursor, coarse_cursor);
    part_coarse<<<NT_A, 256, 0, stream>>>(adj_rows, adj_cols, adj_vals,
                                          coarse_cursor, ecv_a);
    part_fine<<<dim3(32, NC), 256, 0, stream>>>(ecv_a, fine_base,
                                                fine_cursor, ecv_b);
    bucket_sort<<<NF, 256, 0, stream>>>(ecv_b, fine_base, ecv_a, row_ptr);

    // ---- 3 propagation layers, acc update fused ----
    half4* x = x16;
    half4* y = y16;
    for (int l = 0; l < N_LAYERS; ++l) {
        bool last = (l == N_LAYERS - 1);
        int grid = (N_NODES + 3) / 4;   // 4 waves (rows) per 256-thread block
        spmm_csr<<<grid, 256, 0, stream>>>(
            row_ptr, ecv_a, x, y, acc,
            last ? 0.25f : 1.0f, last ? 0 : 1);
        half4* tmp = x; x = y; y = tmp;
    }
}